// Round 4
// baseline (9218.297 us; speedup 1.0000x reference)
//
#include <hip/hip_runtime.h>
#include <hip/hip_bf16.h>

// ProcessNeurons: B=8, S=2048, K_IN=128, D_MODEL=1024, N_INPUT=256,
// N_PROC=1024, K_PROC=256. Inputs fp32 (+int32 idx), output fp32.
// (R3 post-mortem: fp32-in proven by crash asymmetry; fp32-out per harness
//  contract — R2's bf16 out-writes produced the 4.27 absmax signature.)
#define NB    8
#define NS    2048
#define NKIN  128
#define NPROC 1024
#define NIN   256
#define NDM   1024
#define NKP   256
#define SSPLIT 4

typedef unsigned short u16;
typedef unsigned int   u32;
typedef __attribute__((ext_vector_type(4))) u16   u16x4;
typedef __attribute__((ext_vector_type(8))) u16   u16x8;
typedef __attribute__((ext_vector_type(4))) float f32x4;

__device__ __forceinline__ float bf2f(u16 u) {
    union { u32 i; float f; } v; v.i = ((u32)u) << 16; return v.f;
}
__device__ __forceinline__ u16 f2bf(float f) {
    u32 x = __float_as_uint(f);
    u32 r = (x + 0x7FFFu + ((x >> 16) & 1u)) >> 16;   // RNE
    return (u16)r;
}
__device__ __forceinline__ float gelu_exact(float x) {
    return 0.5f * x * (1.0f + erff(x * 0.70710678118654752f));
}
__device__ __forceinline__ int clampi(int v, int hi) {   // defensive: keep
    return v < 0 ? 0 : (v > hi ? hi : v);                // gathers in-bounds
}

// ---------------------------------------------------------------------------
// K1: scores[seg,b,p] = sum_{s in seg} gelu( sum_k A[b,s,k]*W[p,idx[b,k]] )
// grid (NPROC/64, NB, SSPLIT), block 256 (16x16, 4x4 micro-tile).
// ---------------------------------------------------------------------------
__global__ __launch_bounds__(256) void k1_scores(
        const float* __restrict__ A, const float* __restrict__ W,
        const int* __restrict__ idx, float* __restrict__ scores) {
    const int p0   = blockIdx.x * 64;
    const int b    = blockIdx.y;
    const int sseg = blockIdx.z;
    const int tid  = threadIdx.x;
    const int tx   = tid & 15;   // p dir
    const int ty   = tid >> 4;   // s dir

    __shared__ int   idxs[NKIN];
    __shared__ float Ws[NKIN][68];   // [k][pp]
    __shared__ float As[64][132];    // [s-row][k]
    __shared__ float red[16][64];

    if (tid < NKIN) idxs[tid] = clampi(idx[b * NKIN + tid], NIN - 1);
    __syncthreads();
    for (int e = tid; e < NKIN * 64; e += 256) {
        int k = e >> 6, pp = e & 63;
        Ws[k][pp] = W[(p0 + pp) * NIN + idxs[k]];
    }

    float cs[4] = {0.f, 0.f, 0.f, 0.f};
    const int stiles = (NS / 64) / SSPLIT;   // 8
    for (int st = 0; st < stiles; ++st) {
        const int s0 = (sseg * stiles + st) * 64;
        __syncthreads();
        for (int e = tid; e < 64 * 32; e += 256) {   // 64 rows x 32 float4
            int r = e >> 5, g = e & 31;
            *(f32x4*)&As[r][g * 4] =
                *(const f32x4*)&A[(size_t)(b * NS + s0 + r) * NKIN + g * 4];
        }
        __syncthreads();

        float acc[4][4] = {};
        for (int k = 0; k < NKIN; k += 4) {
            f32x4 af[4];
            #pragma unroll
            for (int i = 0; i < 4; ++i) af[i] = *(const f32x4*)&As[ty * 4 + i][k];
            #pragma unroll
            for (int kk = 0; kk < 4; ++kk) {
                f32x4 wv = *(const f32x4*)&Ws[k + kk][tx * 4];
                #pragma unroll
                for (int i = 0; i < 4; ++i) {
                    acc[i][0] = fmaf(af[i][kk], wv[0], acc[i][0]);
                    acc[i][1] = fmaf(af[i][kk], wv[1], acc[i][1]);
                    acc[i][2] = fmaf(af[i][kk], wv[2], acc[i][2]);
                    acc[i][3] = fmaf(af[i][kk], wv[3], acc[i][3]);
                }
            }
        }
        #pragma unroll
        for (int i = 0; i < 4; ++i)
            #pragma unroll
            for (int j = 0; j < 4; ++j)
                cs[j] += gelu_exact(acc[i][j]);
    }

    __syncthreads();
    #pragma unroll
    for (int j = 0; j < 4; ++j) red[ty][tx * 4 + j] = cs[j];
    __syncthreads();
    if (tid < 64) {
        float s = 0.f;
        #pragma unroll
        for (int r = 0; r < 16; ++r) s += red[r][tid];
        scores[(sseg * NB + b) * NPROC + p0 + tid] = s;
    }
}

// ---------------------------------------------------------------------------
// K2: top-k by stable rank count (value desc, index asc == lax.top_k).
// grid NB, block 256, 4 neurons/thread.
// ---------------------------------------------------------------------------
__global__ __launch_bounds__(256) void k2_topk(
        const float* __restrict__ scores, int* __restrict__ topk) {
    const int b = blockIdx.x;
    __shared__ float sc[NPROC];
    #pragma unroll
    for (int q = 0; q < 4; ++q) {
        int p = q * 256 + threadIdx.x;
        float v = 0.f;
        #pragma unroll
        for (int seg = 0; seg < SSPLIT; ++seg)
            v += scores[(seg * NB + b) * NPROC + p];
        sc[p] = v;
    }
    __syncthreads();
    #pragma unroll
    for (int q = 0; q < 4; ++q) {
        int p = q * 256 + threadIdx.x;
        float v = sc[p];
        int rank = 0;
        for (int j = 0; j < NPROC; ++j) {
            float sj = sc[j];
            rank += (sj > v) || (sj == v && j < p);
        }
        if (rank < NKP) topk[b * NKP + rank] = p;
    }
}

// ---------------------------------------------------------------------------
// K3: sel[b,s,c] = gelu( sum_k A[b,s,k] * W[topk[b,c], idx[b,k]] ), bf16.
// grid (NKP/64, NB, NS/64), block 256.
// ---------------------------------------------------------------------------
__global__ __launch_bounds__(256) void k3_selacts(
        const float* __restrict__ A, const float* __restrict__ W,
        const int* __restrict__ idx, const int* __restrict__ topk,
        u16* __restrict__ sel) {
    const int c0 = blockIdx.x * 64;
    const int b  = blockIdx.y;
    const int s0 = blockIdx.z * 64;
    const int tid = threadIdx.x;
    const int tx  = tid & 15;
    const int ty  = tid >> 4;

    __shared__ int   idxs[NKIN];
    __shared__ int   tcol[64];
    __shared__ float Ws[NKIN][68];
    __shared__ float As[64][132];

    if (tid < NKIN) idxs[tid] = clampi(idx[b * NKIN + tid], NIN - 1);
    if (tid >= 128 && tid < 192)
        tcol[tid - 128] = clampi(topk[b * NKP + c0 + tid - 128], NPROC - 1);
    __syncthreads();
    for (int e = tid; e < NKIN * 64; e += 256) {
        int k = e >> 6, pp = e & 63;
        Ws[k][pp] = W[tcol[pp] * NIN + idxs[k]];
    }
    for (int e = tid; e < 64 * 32; e += 256) {
        int r = e >> 5, g = e & 31;
        *(f32x4*)&As[r][g * 4] =
            *(const f32x4*)&A[(size_t)(b * NS + s0 + r) * NKIN + g * 4];
    }
    __syncthreads();

    float acc[4][4] = {};
    for (int k = 0; k < NKIN; k += 4) {
        f32x4 af[4];
        #pragma unroll
        for (int i = 0; i < 4; ++i) af[i] = *(const f32x4*)&As[ty * 4 + i][k];
        #pragma unroll
        for (int kk = 0; kk < 4; ++kk) {
            f32x4 wv = *(const f32x4*)&Ws[k + kk][tx * 4];
            #pragma unroll
            for (int i = 0; i < 4; ++i) {
                acc[i][0] = fmaf(af[i][kk], wv[0], acc[i][0]);
                acc[i][1] = fmaf(af[i][kk], wv[1], acc[i][1]);
                acc[i][2] = fmaf(af[i][kk], wv[2], acc[i][2]);
                acc[i][3] = fmaf(af[i][kk], wv[3], acc[i][3]);
            }
        }
    }
    #pragma unroll
    for (int i = 0; i < 4; ++i) {
        u16x4 ov;
        #pragma unroll
        for (int j = 0; j < 4; ++j) ov[j] = f2bf(gelu_exact(acc[i][j]));
        *(u16x4*)&sel[(size_t)(b * NS + s0 + ty * 4 + i) * NKP + c0 + tx * 4] = ov;
    }
}

// ---------------------------------------------------------------------------
// K4: out[b,s,d] = sum_c sel[b,s,c] * PO[topk[b,c], d], fp32 out.
// grid (NDM/64, NS/64, NB), block 256.
// ---------------------------------------------------------------------------
__global__ __launch_bounds__(256) void k4_out(
        const u16* __restrict__ sel, const float* __restrict__ PO,
        const int* __restrict__ topk, float* __restrict__ out) {
    const int d0 = blockIdx.x * 64;
    const int s0 = blockIdx.y * 64;
    const int b  = blockIdx.z;
    const int tid = threadIdx.x;
    const int tx  = tid & 15;   // d dir
    const int ty  = tid >> 4;   // s dir

    __shared__ int   tloc[NKP];
    __shared__ float Asel[64][68];   // [s-row][k]
    __shared__ float Bsel[64][68];   // [k][d]

    tloc[tid] = clampi(topk[b * NKP + tid], NPROC - 1);

    float acc[4][4] = {};
    for (int k0 = 0; k0 < NKP; k0 += 64) {
        __syncthreads();   // covers tloc on first iter, tile reuse after
        for (int e = tid; e < 64 * 8; e += 256) {   // sel rows (bf16)
            int r = e >> 3, g = e & 7;
            u16x8 v = *(const u16x8*)&sel[(size_t)(b * NS + s0 + r) * NKP + k0 + g * 8];
            #pragma unroll
            for (int j = 0; j < 8; ++j) Asel[r][g * 8 + j] = bf2f(v[j]);
        }
        for (int e = tid; e < 64 * 16; e += 256) {  // PO rows (gathered, fp32)
            int r = e >> 4, g = e & 15;
            *(f32x4*)&Bsel[r][g * 4] =
                *(const f32x4*)&PO[(size_t)tloc[k0 + r] * NDM + d0 + g * 4];
        }
        __syncthreads();

        for (int k = 0; k < 64; k += 4) {
            f32x4 af[4];
            #pragma unroll
            for (int i = 0; i < 4; ++i) af[i] = *(const f32x4*)&Asel[ty * 4 + i][k];
            #pragma unroll
            for (int kk = 0; kk < 4; ++kk) {
                f32x4 wv = *(const f32x4*)&Bsel[k + kk][tx * 4];
                #pragma unroll
                for (int i = 0; i < 4; ++i) {
                    acc[i][0] = fmaf(af[i][kk], wv[0], acc[i][0]);
                    acc[i][1] = fmaf(af[i][kk], wv[1], acc[i][1]);
                    acc[i][2] = fmaf(af[i][kk], wv[2], acc[i][2]);
                    acc[i][3] = fmaf(af[i][kk], wv[3], acc[i][3]);
                }
            }
        }
    }
    #pragma unroll
    for (int i = 0; i < 4; ++i) {
        f32x4 ov;
        #pragma unroll
        for (int j = 0; j < 4; ++j) ov[j] = acc[i][j];
        *(f32x4*)&out[(size_t)(b * NS + s0 + ty * 4 + i) * NDM + d0 + tx * 4] = ov;
    }
}

// ---------------------------------------------------------------------------
extern "C" void kernel_launch(void* const* d_in, const int* in_sizes, int n_in,
                              void* d_out, int out_size, void* d_ws, size_t ws_size,
                              hipStream_t stream) {
    (void)in_sizes; (void)n_in; (void)out_size; (void)ws_size;
    const float* A   = (const float*)d_in[0];   // (B,S,K_IN) fp32
    const float* W   = (const float*)d_in[1];   // (N_PROC,N_INPUT) fp32
    const float* PO  = (const float*)d_in[2];   // (N_PROC,D_MODEL) fp32
    const int*   idx = (const int*)d_in[3];     // (B,K_IN) int32
    float* out = (float*)d_out;                 // (B,S,D_MODEL) fp32

    // workspace: sel (8,388,608 B) | scores (131,072 B) | topk (8,192 B)
    char* w = (char*)d_ws;
    u16*   sel    = (u16*)w;
    float* scores = (float*)(w + (size_t)8388608);
    int*   topk   = (int*)(w + (size_t)8388608 + 131072);

    k1_scores<<<dim3(NPROC / 64, NB, SSPLIT), 256, 0, stream>>>(A, W, idx, scores);
    k2_topk<<<NB, 256, 0, stream>>>(scores, topk);
    k3_selacts<<<dim3(NKP / 64, NB, NS / 64), 256, 0, stream>>>(A, W, idx, topk, sel);
    k4_out<<<dim3(NDM / 64, NS / 64, NB), 256, 0, stream>>>(sel, PO, topk, out);
}

// Round 5
// 258.640 us; speedup vs baseline: 35.6414x; 35.6414x over previous
//
#include <hip/hip_runtime.h>
#include <hip/hip_bf16.h>

// ProcessNeurons: B=8, S=2048, K_IN=128, D_MODEL=1024, N_INPUT=256,
// N_PROC=1024, K_PROC=256. Inputs fp32 (+int32 idx), output fp32.
// R4: passed (absmax 0.0156). R5: k4 rewritten as bf16 MFMA GEMM — old k4
// spilled (VGPR=256, 5.8GB scratch writes) and was 86% of runtime.
#define NB    8
#define NS    2048
#define NKIN  128
#define NPROC 1024
#define NIN   256
#define NDM   1024
#define NKP   256
#define SSPLIT 4

typedef unsigned short u16;
typedef unsigned int   u32;
typedef __attribute__((ext_vector_type(4))) u16   u16x4;
typedef __attribute__((ext_vector_type(8))) u16   u16x8;
typedef __attribute__((ext_vector_type(4))) float f32x4;
typedef __attribute__((ext_vector_type(8))) short bf16x8;   // MFMA A/B frag
typedef __attribute__((ext_vector_type(4))) float f32x4v;   // MFMA C/D frag

__device__ __forceinline__ float bf2f(u16 u) {
    union { u32 i; float f; } v; v.i = ((u32)u) << 16; return v.f;
}
__device__ __forceinline__ u16 f2bf(float f) {
    u32 x = __float_as_uint(f);
    u32 r = (x + 0x7FFFu + ((x >> 16) & 1u)) >> 16;   // RNE
    return (u16)r;
}
__device__ __forceinline__ float gelu_exact(float x) {
    return 0.5f * x * (1.0f + erff(x * 0.70710678118654752f));
}
__device__ __forceinline__ int clampi(int v, int hi) {
    return v < 0 ? 0 : (v > hi ? hi : v);
}

// ---------------------------------------------------------------------------
// K1: scores[seg,b,p] = sum_{s in seg} gelu( sum_k A[b,s,k]*W[p,idx[b,k]] )
// fp32 throughout — top-k rank gaps ~6e-5 demand fp32-exact scores.
// grid (NPROC/64, NB, SSPLIT), block 256 (16x16, 4x4 micro-tile).
// ---------------------------------------------------------------------------
__global__ __launch_bounds__(256) void k1_scores(
        const float* __restrict__ A, const float* __restrict__ W,
        const int* __restrict__ idx, float* __restrict__ scores) {
    const int p0   = blockIdx.x * 64;
    const int b    = blockIdx.y;
    const int sseg = blockIdx.z;
    const int tid  = threadIdx.x;
    const int tx   = tid & 15;   // p dir
    const int ty   = tid >> 4;   // s dir

    __shared__ int   idxs[NKIN];
    __shared__ float Ws[NKIN][68];
    __shared__ float As[64][132];
    __shared__ float red[16][64];

    if (tid < NKIN) idxs[tid] = clampi(idx[b * NKIN + tid], NIN - 1);
    __syncthreads();
    for (int e = tid; e < NKIN * 64; e += 256) {
        int k = e >> 6, pp = e & 63;
        Ws[k][pp] = W[(p0 + pp) * NIN + idxs[k]];
    }

    float cs[4] = {0.f, 0.f, 0.f, 0.f};
    const int stiles = (NS / 64) / SSPLIT;   // 8
    for (int st = 0; st < stiles; ++st) {
        const int s0 = (sseg * stiles + st) * 64;
        __syncthreads();
        for (int e = tid; e < 64 * 32; e += 256) {
            int r = e >> 5, g = e & 31;
            *(f32x4*)&As[r][g * 4] =
                *(const f32x4*)&A[(size_t)(b * NS + s0 + r) * NKIN + g * 4];
        }
        __syncthreads();

        float acc[4][4] = {};
        for (int k = 0; k < NKIN; k += 4) {
            f32x4 af[4];
            #pragma unroll
            for (int i = 0; i < 4; ++i) af[i] = *(const f32x4*)&As[ty * 4 + i][k];
            #pragma unroll
            for (int kk = 0; kk < 4; ++kk) {
                f32x4 wv = *(const f32x4*)&Ws[k + kk][tx * 4];
                #pragma unroll
                for (int i = 0; i < 4; ++i) {
                    acc[i][0] = fmaf(af[i][kk], wv[0], acc[i][0]);
                    acc[i][1] = fmaf(af[i][kk], wv[1], acc[i][1]);
                    acc[i][2] = fmaf(af[i][kk], wv[2], acc[i][2]);
                    acc[i][3] = fmaf(af[i][kk], wv[3], acc[i][3]);
                }
            }
        }
        #pragma unroll
        for (int i = 0; i < 4; ++i)
            #pragma unroll
            for (int j = 0; j < 4; ++j)
                cs[j] += gelu_exact(acc[i][j]);
    }

    __syncthreads();
    #pragma unroll
    for (int j = 0; j < 4; ++j) red[ty][tx * 4 + j] = cs[j];
    __syncthreads();
    if (tid < 64) {
        float s = 0.f;
        #pragma unroll
        for (int r = 0; r < 16; ++r) s += red[r][tid];
        scores[(sseg * NB + b) * NPROC + p0 + tid] = s;
    }
}

// ---------------------------------------------------------------------------
// K2: top-k by stable rank count (value desc, index asc == lax.top_k).
// ---------------------------------------------------------------------------
__global__ __launch_bounds__(256) void k2_topk(
        const float* __restrict__ scores, int* __restrict__ topk) {
    const int b = blockIdx.x;
    __shared__ float sc[NPROC];
    #pragma unroll
    for (int q = 0; q < 4; ++q) {
        int p = q * 256 + threadIdx.x;
        float v = 0.f;
        #pragma unroll
        for (int seg = 0; seg < SSPLIT; ++seg)
            v += scores[(seg * NB + b) * NPROC + p];
        sc[p] = v;
    }
    __syncthreads();
    #pragma unroll
    for (int q = 0; q < 4; ++q) {
        int p = q * 256 + threadIdx.x;
        float v = sc[p];
        int rank = 0;
        for (int j = 0; j < NPROC; ++j) {
            float sj = sc[j];
            rank += (sj > v) || (sj == v && j < p);
        }
        if (rank < NKP) topk[b * NKP + rank] = p;
    }
}

// ---------------------------------------------------------------------------
// K3: sel[b,s,c] = gelu( sum_k A[b,s,k] * W[topk[b,c], idx[b,k]] ), bf16.
// ---------------------------------------------------------------------------
__global__ __launch_bounds__(256) void k3_selacts(
        const float* __restrict__ A, const float* __restrict__ W,
        const int* __restrict__ idx, const int* __restrict__ topk,
        u16* __restrict__ sel) {
    const int c0 = blockIdx.x * 64;
    const int b  = blockIdx.y;
    const int s0 = blockIdx.z * 64;
    const int tid = threadIdx.x;
    const int tx  = tid & 15;
    const int ty  = tid >> 4;

    __shared__ int   idxs[NKIN];
    __shared__ int   tcol[64];
    __shared__ float Ws[NKIN][68];
    __shared__ float As[64][132];

    if (tid < NKIN) idxs[tid] = clampi(idx[b * NKIN + tid], NIN - 1);
    if (tid >= 128 && tid < 192)
        tcol[tid - 128] = clampi(topk[b * NKP + c0 + tid - 128], NPROC - 1);
    __syncthreads();
    for (int e = tid; e < NKIN * 64; e += 256) {
        int k = e >> 6, pp = e & 63;
        Ws[k][pp] = W[tcol[pp] * NIN + idxs[k]];
    }
    for (int e = tid; e < 64 * 32; e += 256) {
        int r = e >> 5, g = e & 31;
        *(f32x4*)&As[r][g * 4] =
            *(const f32x4*)&A[(size_t)(b * NS + s0 + r) * NKIN + g * 4];
    }
    __syncthreads();

    float acc[4][4] = {};
    for (int k = 0; k < NKIN; k += 4) {
        f32x4 af[4];
        #pragma unroll
        for (int i = 0; i < 4; ++i) af[i] = *(const f32x4*)&As[ty * 4 + i][k];
        #pragma unroll
        for (int kk = 0; kk < 4; ++kk) {
            f32x4 wv = *(const f32x4*)&Ws[k + kk][tx * 4];
            #pragma unroll
            for (int i = 0; i < 4; ++i) {
                acc[i][0] = fmaf(af[i][kk], wv[0], acc[i][0]);
                acc[i][1] = fmaf(af[i][kk], wv[1], acc[i][1]);
                acc[i][2] = fmaf(af[i][kk], wv[2], acc[i][2]);
                acc[i][3] = fmaf(af[i][kk], wv[3], acc[i][3]);
            }
        }
    }
    #pragma unroll
    for (int i = 0; i < 4; ++i) {
        u16x4 ov;
        #pragma unroll
        for (int j = 0; j < 4; ++j) ov[j] = f2bf(gelu_exact(acc[i][j]));
        *(u16x4*)&sel[(size_t)(b * NS + s0 + ty * 4 + i) * NKP + c0 + tx * 4] = ov;
    }
}

// ---------------------------------------------------------------------------
// K4 (MFMA): out[b,s,d] = sum_c sel[b,s,c] * PO[topk[b,c], d], fp32 out.
// 128x128 tile, 4 waves (2x2), 4x4 frags/wave, BK=64, mfma_f32_16x16x32_bf16.
// LDS tiles k-contiguous per row, XOR-swizzled (byte ^= (row&7)<<4) both on
// write and read — 128B row stride is a 16-way bank conflict otherwise.
// grid (NDM/128, NS/128, NB), block 256.
// ---------------------------------------------------------------------------
__global__ __launch_bounds__(256) void k4_mfma(
        const u16* __restrict__ sel, const float* __restrict__ PO,
        const int* __restrict__ topk, float* __restrict__ out) {
    const int d0   = blockIdx.x * 128;
    const int s0   = blockIdx.y * 128;
    const int b    = blockIdx.z;
    const int tid  = threadIdx.x;
    const int lane = tid & 63;
    const int wid  = tid >> 6;       // 4 waves
    const int wr   = wid >> 1;       // s half (0/1)
    const int wc   = wid & 1;        // d half (0/1)

    __shared__ int tloc[NKP];
    __shared__ u16 Alds[128 * 64];   // [s-row][k], swizzled
    __shared__ u16 Blds[128 * 64];   // [d-col][k] (B transposed), swizzled

    tloc[tid] = clampi(topk[b * NKP + tid], NPROC - 1);

    f32x4v acc[4][4] = {};           // [m][n] 16x16 frags

    for (int k0 = 0; k0 < NKP; k0 += 64) {
        __syncthreads();             // covers tloc (1st iter) + LDS reuse
        // stage A: sel rows, 16B chunks. task e: row r=e>>3, chunk g=e&7
        for (int e = tid; e < 1024; e += 256) {
            int r = e >> 3, g = e & 7;
            u16x8 v = *(const u16x8*)&sel[(size_t)(b * NS + s0 + r) * NKP + k0 + g * 8];
            int slot = g ^ (r & 7);
            *(u16x8*)&Alds[r * 64 + slot * 8] = v;
        }
        // stage B transposed: task e: k-pair kp=e>>5 (rows 2kp,2kp+1), col grp cg=e&31
        for (int e = tid; e < 1024; e += 256) {
            int kp = e >> 5, cg = e & 31;
            f32x4 p0v = *(const f32x4*)&PO[(size_t)tloc[k0 + kp * 2]     * NDM + d0 + cg * 4];
            f32x4 p1v = *(const f32x4*)&PO[(size_t)tloc[k0 + kp * 2 + 1] * NDM + d0 + cg * 4];
            #pragma unroll
            for (int j = 0; j < 4; ++j) {
                int n = cg * 4 + j;
                u32 pack = (u32)f2bf(p0v[j]) | ((u32)f2bf(p1v[j]) << 16);
                u32 byteoff = (u32)n * 128 + (((u32)kp * 4) ^ (((u32)n & 7) << 4));
                *(u32*)((char*)Blds + byteoff) = pack;
            }
        }
        __syncthreads();

        const int krow   = lane >> 4;          // 0..3
        #pragma unroll
        for (int kk = 0; kk < 2; ++kk) {
            const u32 kbase2 = (u32)(kk * 64 + krow * 16);   // byte offset of 8-elem k-group
            bf16x8 afrag[4], bfrag[4];
            #pragma unroll
            for (int m = 0; m < 4; ++m) {
                u32 row = (u32)(wr * 64 + m * 16 + (lane & 15));
                u32 byteoff = row * 128 + (kbase2 ^ ((row & 7) << 4));
                afrag[m] = *(const bf16x8*)((const char*)Alds + byteoff);
            }
            #pragma unroll
            for (int n = 0; n < 4; ++n) {
                u32 col = (u32)(wc * 64 + n * 16 + (lane & 15));
                u32 byteoff = col * 128 + (kbase2 ^ ((col & 7) << 4));
                bfrag[n] = *(const bf16x8*)((const char*)Blds + byteoff);
            }
            #pragma unroll
            for (int m = 0; m < 4; ++m)
                #pragma unroll
                for (int n = 0; n < 4; ++n)
                    acc[m][n] = __builtin_amdgcn_mfma_f32_16x16x32_bf16(
                        afrag[m], bfrag[n], acc[m][n], 0, 0, 0);
        }
    }

    // C/D layout (m89-verified): col = lane&15, row = (lane>>4)*4 + reg
    #pragma unroll
    for (int m = 0; m < 4; ++m) {
        const int rbase = s0 + wr * 64 + m * 16 + (lane >> 4) * 4;
        #pragma unroll
        for (int n = 0; n < 4; ++n) {
            const int col = d0 + wc * 64 + n * 16 + (lane & 15);
            #pragma unroll
            for (int j = 0; j < 4; ++j)
                out[(size_t)(b * NS + rbase + j) * NDM + col] = acc[m][n][j];
        }
    }
}

// ---------------------------------------------------------------------------
extern "C" void kernel_launch(void* const* d_in, const int* in_sizes, int n_in,
                              void* d_out, int out_size, void* d_ws, size_t ws_size,
                              hipStream_t stream) {
    (void)in_sizes; (void)n_in; (void)out_size; (void)ws_size;
    const float* A   = (const float*)d_in[0];   // (B,S,K_IN) fp32
    const float* W   = (const float*)d_in[1];   // (N_PROC,N_INPUT) fp32
    const float* PO  = (const float*)d_in[2];   // (N_PROC,D_MODEL) fp32
    const int*   idx = (const int*)d_in[3];     // (B,K_IN) int32
    float* out = (float*)d_out;                 // (B,S,D_MODEL) fp32

    // workspace: sel (8,388,608 B) | scores (131,072 B) | topk (8,192 B)
    char* w = (char*)d_ws;
    u16*   sel    = (u16*)w;
    float* scores = (float*)(w + (size_t)8388608);
    int*   topk   = (int*)(w + (size_t)8388608 + 131072);

    k1_scores<<<dim3(NPROC / 64, NB, SSPLIT), 256, 0, stream>>>(A, W, idx, scores);
    k2_topk<<<NB, 256, 0, stream>>>(scores, topk);
    k3_selacts<<<dim3(NKP / 64, NB, NS / 64), 256, 0, stream>>>(A, W, idx, topk, sel);
    k4_mfma<<<dim3(NDM / 128, NS / 128, NB), 256, 0, stream>>>(sel, PO, topk, out);
}

// Round 6
// 183.608 us; speedup vs baseline: 50.2065x; 1.4087x over previous
//
#include <hip/hip_runtime.h>
#include <hip/hip_bf16.h>

// ProcessNeurons: B=8, S=2048, K_IN=128, D_MODEL=1024, N_INPUT=256,
// N_PROC=1024, K_PROC=256. Inputs fp32 (+int32 idx), output fp32.
// R4: pass 9218us. R5: k4->MFMA, 258us. R6: k2 parallelized (was 105us,
// 0.35% occupancy latency-bound serial scan).
#define NB    8
#define NS    2048
#define NKIN  128
#define NPROC 1024
#define NIN   256
#define NDM   1024
#define NKP   256
#define SSPLIT 4

typedef unsigned short u16;
typedef unsigned int   u32;
typedef __attribute__((ext_vector_type(4))) u16   u16x4;
typedef __attribute__((ext_vector_type(8))) u16   u16x8;
typedef __attribute__((ext_vector_type(4))) float f32x4;
typedef __attribute__((ext_vector_type(8))) short bf16x8;   // MFMA A/B frag
typedef __attribute__((ext_vector_type(4))) float f32x4v;   // MFMA C/D frag

__device__ __forceinline__ float bf2f(u16 u) {
    union { u32 i; float f; } v; v.i = ((u32)u) << 16; return v.f;
}
__device__ __forceinline__ u16 f2bf(float f) {
    u32 x = __float_as_uint(f);
    u32 r = (x + 0x7FFFu + ((x >> 16) & 1u)) >> 16;   // RNE
    return (u16)r;
}
__device__ __forceinline__ float gelu_exact(float x) {
    return 0.5f * x * (1.0f + erff(x * 0.70710678118654752f));
}
__device__ __forceinline__ int clampi(int v, int hi) {
    return v < 0 ? 0 : (v > hi ? hi : v);
}

// ---------------------------------------------------------------------------
// K1: scores[seg,b,p] = sum_{s in seg} gelu( sum_k A[b,s,k]*W[p,idx[b,k]] )
// fp32 throughout — top-k rank gaps ~2e-5 demand fp32-exact scores.
// grid (NPROC/64, NB, SSPLIT), block 256 (16x16, 4x4 micro-tile).
// ---------------------------------------------------------------------------
__global__ __launch_bounds__(256) void k1_scores(
        const float* __restrict__ A, const float* __restrict__ W,
        const int* __restrict__ idx, float* __restrict__ scores) {
    const int p0   = blockIdx.x * 64;
    const int b    = blockIdx.y;
    const int sseg = blockIdx.z;
    const int tid  = threadIdx.x;
    const int tx   = tid & 15;   // p dir
    const int ty   = tid >> 4;   // s dir

    __shared__ int   idxs[NKIN];
    __shared__ float Ws[NKIN][68];
    __shared__ float As[64][132];
    __shared__ float red[16][64];

    if (tid < NKIN) idxs[tid] = clampi(idx[b * NKIN + tid], NIN - 1);
    __syncthreads();
    for (int e = tid; e < NKIN * 64; e += 256) {
        int k = e >> 6, pp = e & 63;
        Ws[k][pp] = W[(p0 + pp) * NIN + idxs[k]];
    }

    float cs[4] = {0.f, 0.f, 0.f, 0.f};
    const int stiles = (NS / 64) / SSPLIT;   // 8
    for (int st = 0; st < stiles; ++st) {
        const int s0 = (sseg * stiles + st) * 64;
        __syncthreads();
        for (int e = tid; e < 64 * 32; e += 256) {
            int r = e >> 5, g = e & 31;
            *(f32x4*)&As[r][g * 4] =
                *(const f32x4*)&A[(size_t)(b * NS + s0 + r) * NKIN + g * 4];
        }
        __syncthreads();

        float acc[4][4] = {};
        for (int k = 0; k < NKIN; k += 4) {
            f32x4 af[4];
            #pragma unroll
            for (int i = 0; i < 4; ++i) af[i] = *(const f32x4*)&As[ty * 4 + i][k];
            #pragma unroll
            for (int kk = 0; kk < 4; ++kk) {
                f32x4 wv = *(const f32x4*)&Ws[k + kk][tx * 4];
                #pragma unroll
                for (int i = 0; i < 4; ++i) {
                    acc[i][0] = fmaf(af[i][kk], wv[0], acc[i][0]);
                    acc[i][1] = fmaf(af[i][kk], wv[1], acc[i][1]);
                    acc[i][2] = fmaf(af[i][kk], wv[2], acc[i][2]);
                    acc[i][3] = fmaf(af[i][kk], wv[3], acc[i][3]);
                }
            }
        }
        #pragma unroll
        for (int i = 0; i < 4; ++i)
            #pragma unroll
            for (int j = 0; j < 4; ++j)
                cs[j] += gelu_exact(acc[i][j]);
    }

    __syncthreads();
    #pragma unroll
    for (int j = 0; j < 4; ++j) red[ty][tx * 4 + j] = cs[j];
    __syncthreads();
    if (tid < 64) {
        float s = 0.f;
        #pragma unroll
        for (int r = 0; r < 16; ++r) s += red[r][tid];
        scores[(sseg * NB + b) * NPROC + p0 + tid] = s;
    }
}

// ---------------------------------------------------------------------------
// K2: top-k by stable rank count (value desc, index asc == lax.top_k).
// R6: parallelized — grid (NB,4), 256 threads, 1 p/thread, f32x4 LDS scan
// (broadcast reads, conflict-free). Was: 8 blocks, serial scalar scan.
// ---------------------------------------------------------------------------
__global__ __launch_bounds__(256) void k2_topk(
        const float* __restrict__ scores, int* __restrict__ topk) {
    const int b  = blockIdx.x;
    const int pc = blockIdx.y;   // p-chunk 0..3
    __shared__ float sc[NPROC];
    #pragma unroll
    for (int q = 0; q < 4; ++q) {
        int p = q * 256 + threadIdx.x;
        float v = 0.f;
        #pragma unroll
        for (int seg = 0; seg < SSPLIT; ++seg)
            v += scores[(seg * NB + b) * NPROC + p];
        sc[p] = v;
    }
    __syncthreads();
    const int p = pc * 256 + threadIdx.x;
    const float v = sc[p];
    int rank = 0;
    #pragma unroll 4
    for (int jj = 0; jj < NPROC / 4; ++jj) {
        f32x4 s4 = *(const f32x4*)&sc[jj * 4];
        #pragma unroll
        for (int c = 0; c < 4; ++c) {
            int j = jj * 4 + c;
            rank += (s4[c] > v) || (s4[c] == v && j < p);
        }
    }
    if (rank < NKP) topk[b * NKP + rank] = p;
}

// ---------------------------------------------------------------------------
// K3: sel[b,s,c] = gelu( sum_k A[b,s,k] * W[topk[b,c], idx[b,k]] ), bf16.
// ---------------------------------------------------------------------------
__global__ __launch_bounds__(256) void k3_selacts(
        const float* __restrict__ A, const float* __restrict__ W,
        const int* __restrict__ idx, const int* __restrict__ topk,
        u16* __restrict__ sel) {
    const int c0 = blockIdx.x * 64;
    const int b  = blockIdx.y;
    const int s0 = blockIdx.z * 64;
    const int tid = threadIdx.x;
    const int tx  = tid & 15;
    const int ty  = tid >> 4;

    __shared__ int   idxs[NKIN];
    __shared__ int   tcol[64];
    __shared__ float Ws[NKIN][68];
    __shared__ float As[64][132];

    if (tid < NKIN) idxs[tid] = clampi(idx[b * NKIN + tid], NIN - 1);
    if (tid >= 128 && tid < 192)
        tcol[tid - 128] = clampi(topk[b * NKP + c0 + tid - 128], NPROC - 1);
    __syncthreads();
    for (int e = tid; e < NKIN * 64; e += 256) {
        int k = e >> 6, pp = e & 63;
        Ws[k][pp] = W[tcol[pp] * NIN + idxs[k]];
    }
    for (int e = tid; e < 64 * 32; e += 256) {
        int r = e >> 5, g = e & 31;
        *(f32x4*)&As[r][g * 4] =
            *(const f32x4*)&A[(size_t)(b * NS + s0 + r) * NKIN + g * 4];
    }
    __syncthreads();

    float acc[4][4] = {};
    for (int k = 0; k < NKIN; k += 4) {
        f32x4 af[4];
        #pragma unroll
        for (int i = 0; i < 4; ++i) af[i] = *(const f32x4*)&As[ty * 4 + i][k];
        #pragma unroll
        for (int kk = 0; kk < 4; ++kk) {
            f32x4 wv = *(const f32x4*)&Ws[k + kk][tx * 4];
            #pragma unroll
            for (int i = 0; i < 4; ++i) {
                acc[i][0] = fmaf(af[i][kk], wv[0], acc[i][0]);
                acc[i][1] = fmaf(af[i][kk], wv[1], acc[i][1]);
                acc[i][2] = fmaf(af[i][kk], wv[2], acc[i][2]);
                acc[i][3] = fmaf(af[i][kk], wv[3], acc[i][3]);
            }
        }
    }
    #pragma unroll
    for (int i = 0; i < 4; ++i) {
        u16x4 ov;
        #pragma unroll
        for (int j = 0; j < 4; ++j) ov[j] = f2bf(gelu_exact(acc[i][j]));
        *(u16x4*)&sel[(size_t)(b * NS + s0 + ty * 4 + i) * NKP + c0 + tx * 4] = ov;
    }
}

// ---------------------------------------------------------------------------
// K4 (MFMA): out[b,s,d] = sum_c sel[b,s,c] * PO[topk[b,c], d], fp32 out.
// 128x128 tile, 4 waves (2x2), 4x4 frags/wave, BK=64, mfma_f32_16x16x32_bf16.
// LDS tiles k-contiguous per row, XOR-swizzled both sides.
// grid (NDM/128, NS/128, NB), block 256.
// ---------------------------------------------------------------------------
__global__ __launch_bounds__(256) void k4_mfma(
        const u16* __restrict__ sel, const float* __restrict__ PO,
        const int* __restrict__ topk, float* __restrict__ out) {
    const int d0   = blockIdx.x * 128;
    const int s0   = blockIdx.y * 128;
    const int b    = blockIdx.z;
    const int tid  = threadIdx.x;
    const int lane = tid & 63;
    const int wid  = tid >> 6;       // 4 waves
    const int wr   = wid >> 1;       // s half (0/1)
    const int wc   = wid & 1;        // d half (0/1)

    __shared__ int tloc[NKP];
    __shared__ u16 Alds[128 * 64];   // [s-row][k], swizzled
    __shared__ u16 Blds[128 * 64];   // [d-col][k] (B transposed), swizzled

    tloc[tid] = clampi(topk[b * NKP + tid], NPROC - 1);

    f32x4v acc[4][4] = {};           // [m][n] 16x16 frags

    for (int k0 = 0; k0 < NKP; k0 += 64) {
        __syncthreads();             // covers tloc (1st iter) + LDS reuse
        for (int e = tid; e < 1024; e += 256) {
            int r = e >> 3, g = e & 7;
            u16x8 v = *(const u16x8*)&sel[(size_t)(b * NS + s0 + r) * NKP + k0 + g * 8];
            int slot = g ^ (r & 7);
            *(u16x8*)&Alds[r * 64 + slot * 8] = v;
        }
        for (int e = tid; e < 1024; e += 256) {
            int kp = e >> 5, cg = e & 31;
            f32x4 p0v = *(const f32x4*)&PO[(size_t)tloc[k0 + kp * 2]     * NDM + d0 + cg * 4];
            f32x4 p1v = *(const f32x4*)&PO[(size_t)tloc[k0 + kp * 2 + 1] * NDM + d0 + cg * 4];
            #pragma unroll
            for (int j = 0; j < 4; ++j) {
                int n = cg * 4 + j;
                u32 pack = (u32)f2bf(p0v[j]) | ((u32)f2bf(p1v[j]) << 16);
                u32 byteoff = (u32)n * 128 + (((u32)kp * 4) ^ (((u32)n & 7) << 4));
                *(u32*)((char*)Blds + byteoff) = pack;
            }
        }
        __syncthreads();

        const int krow = lane >> 4;          // 0..3
        #pragma unroll
        for (int kk = 0; kk < 2; ++kk) {
            const u32 kbase2 = (u32)(kk * 64 + krow * 16);
            bf16x8 afrag[4], bfrag[4];
            #pragma unroll
            for (int m = 0; m < 4; ++m) {
                u32 row = (u32)(wr * 64 + m * 16 + (lane & 15));
                u32 byteoff = row * 128 + (kbase2 ^ ((row & 7) << 4));
                afrag[m] = *(const bf16x8*)((const char*)Alds + byteoff);
            }
            #pragma unroll
            for (int n = 0; n < 4; ++n) {
                u32 col = (u32)(wc * 64 + n * 16 + (lane & 15));
                u32 byteoff = col * 128 + (kbase2 ^ ((col & 7) << 4));
                bfrag[n] = *(const bf16x8*)((const char*)Blds + byteoff);
            }
            #pragma unroll
            for (int m = 0; m < 4; ++m)
                #pragma unroll
                for (int n = 0; n < 4; ++n)
                    acc[m][n] = __builtin_amdgcn_mfma_f32_16x16x32_bf16(
                        afrag[m], bfrag[n], acc[m][n], 0, 0, 0);
        }
    }

    // C/D layout (m89-verified): col = lane&15, row = (lane>>4)*4 + reg
    #pragma unroll
    for (int m = 0; m < 4; ++m) {
        const int rbase = s0 + wr * 64 + m * 16 + (lane >> 4) * 4;
        #pragma unroll
        for (int n = 0; n < 4; ++n) {
            const int col = d0 + wc * 64 + n * 16 + (lane & 15);
            #pragma unroll
            for (int j = 0; j < 4; ++j)
                out[(size_t)(b * NS + rbase + j) * NDM + col] = acc[m][n][j];
        }
    }
}

// ---------------------------------------------------------------------------
extern "C" void kernel_launch(void* const* d_in, const int* in_sizes, int n_in,
                              void* d_out, int out_size, void* d_ws, size_t ws_size,
                              hipStream_t stream) {
    (void)in_sizes; (void)n_in; (void)out_size; (void)ws_size;
    const float* A   = (const float*)d_in[0];   // (B,S,K_IN) fp32
    const float* W   = (const float*)d_in[1];   // (N_PROC,N_INPUT) fp32
    const float* PO  = (const float*)d_in[2];   // (N_PROC,D_MODEL) fp32
    const int*   idx = (const int*)d_in[3];     // (B,K_IN) int32
    float* out = (float*)d_out;                 // (B,S,D_MODEL) fp32

    // workspace: sel (8,388,608 B) | scores (131,072 B) | topk (8,192 B)
    char* w = (char*)d_ws;
    u16*   sel    = (u16*)w;
    float* scores = (float*)(w + (size_t)8388608);
    int*   topk   = (int*)(w + (size_t)8388608 + 131072);

    k1_scores<<<dim3(NPROC / 64, NB, SSPLIT), 256, 0, stream>>>(A, W, idx, scores);
    k2_topk<<<dim3(NB, 4), 256, 0, stream>>>(scores, topk);
    k3_selacts<<<dim3(NKP / 64, NB, NS / 64), 256, 0, stream>>>(A, W, idx, topk, sel);
    k4_mfma<<<dim3(NDM / 128, NS / 128, NB), 256, 0, stream>>>(sel, PO, topk, out);
}

// Round 7
// 167.098 us; speedup vs baseline: 55.1671x; 1.0988x over previous
//
#include <hip/hip_runtime.h>
#include <hip/hip_bf16.h>

// ProcessNeurons: B=8, S=2048, K_IN=128, D_MODEL=1024, N_INPUT=256,
// N_PROC=1024, K_PROC=256. Inputs fp32 (+int32 idx), output fp32.
// R5: k4->MFMA (9218->258us). R6: k2 parallel (->183us). R7: k1 -> 3-pass
// split-precision bf16 MFMA (hi*hi+hi*lo+lo*hi, score err ~2e-7 << min
// top-k gap ~1e-5); k3 -> single-pass bf16 MFMA; k0 pre-gathers W.
#define NB    8
#define NS    2048
#define NKIN  128
#define NPROC 1024
#define NIN   256
#define NDM   1024
#define NKP   256
#define NSEG  16     // k1 S-segments (NS/128)

typedef unsigned short u16;
typedef unsigned int   u32;
typedef __attribute__((ext_vector_type(4))) u16   u16x4;
typedef __attribute__((ext_vector_type(8))) u16   u16x8;
typedef __attribute__((ext_vector_type(4))) float f32x4;
typedef __attribute__((ext_vector_type(8))) short bf16x8;   // MFMA A/B frag
typedef __attribute__((ext_vector_type(4))) float f32x4v;   // MFMA C/D frag

__device__ __forceinline__ float bf2f(u16 u) {
    union { u32 i; float f; } v; v.i = ((u32)u) << 16; return v.f;
}
__device__ __forceinline__ u16 f2bf(float f) {
    u32 x = __float_as_uint(f);
    u32 r = (x + 0x7FFFu + ((x >> 16) & 1u)) >> 16;   // RNE
    return (u16)r;
}
__device__ __forceinline__ float gelu_exact(float x) {
    return 0.5f * x * (1.0f + erff(x * 0.70710678118654752f));
}
__device__ __forceinline__ int clampi(int v, int hi) {
    return v < 0 ? 0 : (v > hi ? hi : v);
}

// ---------------------------------------------------------------------------
// K0: pre-gather + split W columns: Wg{Hi,Lo}[b][p][k] = split(W[p, idx[b,k]])
// grid (NB, NPROC/128), block 256. Gathers hit L1/L2 (W = 1MB); writes coalesced.
// ---------------------------------------------------------------------------
__global__ __launch_bounds__(256) void k0_prep(
        const float* __restrict__ W, const int* __restrict__ idx,
        u16* __restrict__ WgHi, u16* __restrict__ WgLo) {
    const int b  = blockIdx.x;
    const int p0 = blockIdx.y * 128;
    const int tid = threadIdx.x;
    __shared__ int idxs[NKIN];
    if (tid < NKIN) idxs[tid] = clampi(idx[b * NKIN + tid], NIN - 1);
    __syncthreads();
    for (int e = tid; e < 128 * NKIN; e += 256) {
        int p = p0 + (e >> 7), k = e & 127;
        float x  = W[p * NIN + idxs[k]];
        u16 hi   = f2bf(x);
        u16 lo   = f2bf(x - bf2f(hi));
        size_t o = (size_t)(b * NPROC + p) * NKIN + k;
        WgHi[o] = hi;
        WgLo[o] = lo;
    }
}

// ---------------------------------------------------------------------------
// K1 (split MFMA): scores[seg,b,p] = sum_{s in seg} gelu(sum_k A*Wsel)
// acc = Ahi*Whi + Ahi*Wlo + Alo*Whi (fp32 MFMA accum) — product rel err
// <= 2^-17. 128x128 tile, 4 waves 2x2, BK=64 x 2 chunks. XOR-swizzled LDS.
// grid (NPROC/128, NB, NSEG), block 256.
// ---------------------------------------------------------------------------
__global__ __launch_bounds__(256) void k1_scores(
        const float* __restrict__ A, const u16* __restrict__ WgHi,
        const u16* __restrict__ WgLo, float* __restrict__ scores) {
    const int p0   = blockIdx.x * 128;
    const int b    = blockIdx.y;
    const int s0   = blockIdx.z * 128;
    const int tid  = threadIdx.x;
    const int lane = tid & 63;
    const int wid  = tid >> 6;
    const int wr   = wid >> 1;       // s half
    const int wc   = wid & 1;        // p half

    __shared__ u16  Ahi[128 * 64], Alo[128 * 64];   // [s][k] swizzled, 16KB ea
    __shared__ u16  Wh [128 * 64], Wl [128 * 64];   // [p][k] swizzled
    __shared__ float red[2][128];

    f32x4v acc[4][4] = {};

    for (int kc = 0; kc < 2; ++kc) {
        __syncthreads();
        // stage A chunk: 128 rows x 64 k fp32 -> hi/lo bf16 (task: r, g of 8 floats)
        for (int e = tid; e < 1024; e += 256) {
            int r = e >> 3, g = e & 7;
            const float* ap = &A[(size_t)(b * NS + s0 + r) * NKIN + kc * 64 + g * 8];
            f32x4 va = *(const f32x4*)ap;
            f32x4 vb = *(const f32x4*)(ap + 4);
            u16x8 h, l;
            #pragma unroll
            for (int j = 0; j < 4; ++j) {
                u16 hj = f2bf(va[j]); h[j] = hj; l[j] = f2bf(va[j] - bf2f(hj));
                u16 hk = f2bf(vb[j]); h[j+4] = hk; l[j+4] = f2bf(vb[j] - bf2f(hk));
            }
            u32 off = (u32)r * 128 + (((u32)g ^ ((u32)r & 7)) << 4);
            *(u16x8*)((char*)Ahi + off) = h;
            *(u16x8*)((char*)Alo + off) = l;
        }
        // stage W chunk: 128 p-rows x 64 k bf16 (vector loads from Wg)
        for (int e = tid; e < 1024; e += 256) {
            int pp = e >> 3, g = e & 7;
            size_t src = (size_t)(b * NPROC + p0 + pp) * NKIN + kc * 64 + g * 8;
            u32 off = (u32)pp * 128 + (((u32)g ^ ((u32)pp & 7)) << 4);
            *(u16x8*)((char*)Wh + off) = *(const u16x8*)&WgHi[src];
            *(u16x8*)((char*)Wl + off) = *(const u16x8*)&WgLo[src];
        }
        __syncthreads();

        #pragma unroll
        for (int kk = 0; kk < 2; ++kk) {
            const u32 kbyte = (u32)(kk * 64 + (lane >> 4) * 16);
            bf16x8 ah[4], al[4], wh[4], wl[4];
            #pragma unroll
            for (int m = 0; m < 4; ++m) {
                u32 row = (u32)(wr * 64 + m * 16 + (lane & 15));
                u32 off = row * 128 + (kbyte ^ ((row & 7) << 4));
                ah[m] = *(const bf16x8*)((const char*)Ahi + off);
                al[m] = *(const bf16x8*)((const char*)Alo + off);
            }
            #pragma unroll
            for (int n = 0; n < 4; ++n) {
                u32 col = (u32)(wc * 64 + n * 16 + (lane & 15));
                u32 off = col * 128 + (kbyte ^ ((col & 7) << 4));
                wh[n] = *(const bf16x8*)((const char*)Wh + off);
                wl[n] = *(const bf16x8*)((const char*)Wl + off);
            }
            #pragma unroll
            for (int m = 0; m < 4; ++m)
                #pragma unroll
                for (int n = 0; n < 4; ++n) {
                    acc[m][n] = __builtin_amdgcn_mfma_f32_16x16x32_bf16(
                        ah[m], wh[n], acc[m][n], 0, 0, 0);
                    acc[m][n] = __builtin_amdgcn_mfma_f32_16x16x32_bf16(
                        ah[m], wl[n], acc[m][n], 0, 0, 0);
                    acc[m][n] = __builtin_amdgcn_mfma_f32_16x16x32_bf16(
                        al[m], wh[n], acc[m][n], 0, 0, 0);
                }
        }
    }

    // epilogue: gelu + column (over s) reduction. col = lane&15 within frag.
    float colsum[4] = {0.f, 0.f, 0.f, 0.f};
    #pragma unroll
    for (int n = 0; n < 4; ++n)
        #pragma unroll
        for (int m = 0; m < 4; ++m)
            #pragma unroll
            for (int j = 0; j < 4; ++j)
                colsum[n] += gelu_exact(acc[m][n][j]);
    #pragma unroll
    for (int n = 0; n < 4; ++n) {
        colsum[n] += __shfl_xor(colsum[n], 16, 64);
        colsum[n] += __shfl_xor(colsum[n], 32, 64);
    }
    if (lane < 16) {
        #pragma unroll
        for (int n = 0; n < 4; ++n)
            red[wr][wc * 64 + n * 16 + lane] = colsum[n];
    }
    __syncthreads();
    if (tid < 128)
        scores[(size_t)(blockIdx.z * NB + b) * NPROC + p0 + tid] =
            red[0][tid] + red[1][tid];
}

// ---------------------------------------------------------------------------
// K2: top-k by stable rank count (value desc, index asc == lax.top_k).
// grid (NB,4), 256 threads, fixed-order segment sum (deterministic).
// ---------------------------------------------------------------------------
__global__ __launch_bounds__(256) void k2_topk(
        const float* __restrict__ scores, int* __restrict__ topk) {
    const int b  = blockIdx.x;
    const int pc = blockIdx.y;
    __shared__ float sc[NPROC];
    #pragma unroll
    for (int q = 0; q < 4; ++q) {
        int p = q * 256 + threadIdx.x;
        float v = 0.f;
        #pragma unroll
        for (int seg = 0; seg < NSEG; ++seg)
            v += scores[(size_t)(seg * NB + b) * NPROC + p];
        sc[p] = v;
    }
    __syncthreads();
    const int p = pc * 256 + threadIdx.x;
    const float v = sc[p];
    int rank = 0;
    #pragma unroll 4
    for (int jj = 0; jj < NPROC / 4; ++jj) {
        f32x4 s4 = *(const f32x4*)&sc[jj * 4];
        #pragma unroll
        for (int c = 0; c < 4; ++c) {
            int j = jj * 4 + c;
            rank += (s4[c] > v) || (s4[c] == v && j < p);
        }
    }
    if (rank < NKP) topk[b * NKP + rank] = p;
}

// ---------------------------------------------------------------------------
// K3 (MFMA, hi-only): sel[b,s,c] = gelu(sum_k A*W[topk[b,c]]), bf16 store.
// 128s x 128c tile, K=128 single stage. 256B LDS rows, (row&15) XOR swizzle.
// grid (NKP/128, NB, NS/128), block 256.
// ---------------------------------------------------------------------------
__global__ __launch_bounds__(256) void k3_selacts(
        const float* __restrict__ A, const u16* __restrict__ WgHi,
        const int* __restrict__ topk, u16* __restrict__ sel) {
    const int c0g  = blockIdx.x * 128;
    const int b    = blockIdx.y;
    const int s0   = blockIdx.z * 128;
    const int tid  = threadIdx.x;
    const int lane = tid & 63;
    const int wid  = tid >> 6;
    const int wr   = wid >> 1;
    const int wc   = wid & 1;

    __shared__ int tcol[128];
    __shared__ u16 Ah[128 * 128];   // [s][k] swizzled, 32KB
    __shared__ u16 Ws[128 * 128];   // [c][k] swizzled, 32KB

    if (tid < 128) tcol[tid] = clampi(topk[b * NKP + c0g + tid], NPROC - 1);
    __syncthreads();

    for (int e = tid; e < 2048; e += 256) {   // A: 128 rows x 16 chunks
        int r = e >> 4, g = e & 15;
        const float* ap = &A[(size_t)(b * NS + s0 + r) * NKIN + g * 8];
        f32x4 va = *(const f32x4*)ap;
        f32x4 vb = *(const f32x4*)(ap + 4);
        u16x8 h;
        #pragma unroll
        for (int j = 0; j < 4; ++j) { h[j] = f2bf(va[j]); h[j+4] = f2bf(vb[j]); }
        u32 off = (u32)r * 256 + (((u32)g ^ ((u32)r & 15)) << 4);
        *(u16x8*)((char*)Ah + off) = h;
    }
    for (int e = tid; e < 2048; e += 256) {   // W: 128 c-rows x 16 chunks
        int cc = e >> 4, g = e & 15;
        u32 off = (u32)cc * 256 + (((u32)g ^ ((u32)cc & 15)) << 4);
        *(u16x8*)((char*)Ws + off) =
            *(const u16x8*)&WgHi[(size_t)(b * NPROC + tcol[cc]) * NKIN + g * 8];
    }
    __syncthreads();

    f32x4v acc[4][4] = {};
    #pragma unroll
    for (int ks = 0; ks < 4; ++ks) {
        const u32 kbyte = (u32)(ks * 64 + (lane >> 4) * 16);
        bf16x8 af[4], bf[4];
        #pragma unroll
        for (int m = 0; m < 4; ++m) {
            u32 row = (u32)(wr * 64 + m * 16 + (lane & 15));
            u32 off = row * 256 + (kbyte ^ ((row & 15) << 4));
            af[m] = *(const bf16x8*)((const char*)Ah + off);
        }
        #pragma unroll
        for (int n = 0; n < 4; ++n) {
            u32 col = (u32)(wc * 64 + n * 16 + (lane & 15));
            u32 off = col * 256 + (kbyte ^ ((col & 15) << 4));
            bf[n] = *(const bf16x8*)((const char*)Ws + off);
        }
        #pragma unroll
        for (int m = 0; m < 4; ++m)
            #pragma unroll
            for (int n = 0; n < 4; ++n)
                acc[m][n] = __builtin_amdgcn_mfma_f32_16x16x32_bf16(
                    af[m], bf[n], acc[m][n], 0, 0, 0);
    }

    #pragma unroll
    for (int m = 0; m < 4; ++m) {
        const int rbase = s0 + wr * 64 + m * 16 + (lane >> 4) * 4;
        #pragma unroll
        for (int n = 0; n < 4; ++n) {
            const int col = c0g + wc * 64 + n * 16 + (lane & 15);
            #pragma unroll
            for (int j = 0; j < 4; ++j)
                sel[(size_t)(b * NS + rbase + j) * NKP + col] =
                    f2bf(gelu_exact(acc[m][n][j]));
        }
    }
}

// ---------------------------------------------------------------------------
// K4 (MFMA): out[b,s,d] = sum_c sel[b,s,c] * PO[topk[b,c], d], fp32 out.
// grid (NDM/128, NS/128, NB), block 256.  (unchanged from R5)
// ---------------------------------------------------------------------------
__global__ __launch_bounds__(256) void k4_mfma(
        const u16* __restrict__ sel, const float* __restrict__ PO,
        const int* __restrict__ topk, float* __restrict__ out) {
    const int d0   = blockIdx.x * 128;
    const int s0   = blockIdx.y * 128;
    const int b    = blockIdx.z;
    const int tid  = threadIdx.x;
    const int lane = tid & 63;
    const int wid  = tid >> 6;
    const int wr   = wid >> 1;
    const int wc   = wid & 1;

    __shared__ int tloc[NKP];
    __shared__ u16 Alds[128 * 64];
    __shared__ u16 Blds[128 * 64];

    tloc[tid] = clampi(topk[b * NKP + tid], NPROC - 1);

    f32x4v acc[4][4] = {};

    for (int k0 = 0; k0 < NKP; k0 += 64) {
        __syncthreads();
        for (int e = tid; e < 1024; e += 256) {
            int r = e >> 3, g = e & 7;
            u16x8 v = *(const u16x8*)&sel[(size_t)(b * NS + s0 + r) * NKP + k0 + g * 8];
            int slot = g ^ (r & 7);
            *(u16x8*)&Alds[r * 64 + slot * 8] = v;
        }
        for (int e = tid; e < 1024; e += 256) {
            int kp = e >> 5, cg = e & 31;
            f32x4 p0v = *(const f32x4*)&PO[(size_t)tloc[k0 + kp * 2]     * NDM + d0 + cg * 4];
            f32x4 p1v = *(const f32x4*)&PO[(size_t)tloc[k0 + kp * 2 + 1] * NDM + d0 + cg * 4];
            #pragma unroll
            for (int j = 0; j < 4; ++j) {
                int n = cg * 4 + j;
                u32 pack = (u32)f2bf(p0v[j]) | ((u32)f2bf(p1v[j]) << 16);
                u32 byteoff = (u32)n * 128 + (((u32)kp * 4) ^ (((u32)n & 7) << 4));
                *(u32*)((char*)Blds + byteoff) = pack;
            }
        }
        __syncthreads();

        #pragma unroll
        for (int kk = 0; kk < 2; ++kk) {
            const u32 kbase2 = (u32)(kk * 64 + (lane >> 4) * 16);
            bf16x8 afrag[4], bfrag[4];
            #pragma unroll
            for (int m = 0; m < 4; ++m) {
                u32 row = (u32)(wr * 64 + m * 16 + (lane & 15));
                u32 byteoff = row * 128 + (kbase2 ^ ((row & 7) << 4));
                afrag[m] = *(const bf16x8*)((const char*)Alds + byteoff);
            }
            #pragma unroll
            for (int n = 0; n < 4; ++n) {
                u32 col = (u32)(wc * 64 + n * 16 + (lane & 15));
                u32 byteoff = col * 128 + (kbase2 ^ ((col & 7) << 4));
                bfrag[n] = *(const bf16x8*)((const char*)Blds + byteoff);
            }
            #pragma unroll
            for (int m = 0; m < 4; ++m)
                #pragma unroll
                for (int n = 0; n < 4; ++n)
                    acc[m][n] = __builtin_amdgcn_mfma_f32_16x16x32_bf16(
                        afrag[m], bfrag[n], acc[m][n], 0, 0, 0);
        }
    }

    #pragma unroll
    for (int m = 0; m < 4; ++m) {
        const int rbase = s0 + wr * 64 + m * 16 + (lane >> 4) * 4;
        #pragma unroll
        for (int n = 0; n < 4; ++n) {
            const int col = d0 + wc * 64 + n * 16 + (lane & 15);
            #pragma unroll
            for (int j = 0; j < 4; ++j)
                out[(size_t)(b * NS + rbase + j) * NDM + col] = acc[m][n][j];
        }
    }
}

// ---------------------------------------------------------------------------
extern "C" void kernel_launch(void* const* d_in, const int* in_sizes, int n_in,
                              void* d_out, int out_size, void* d_ws, size_t ws_size,
                              hipStream_t stream) {
    (void)in_sizes; (void)n_in; (void)out_size; (void)ws_size;
    const float* A   = (const float*)d_in[0];   // (B,S,K_IN) fp32
    const float* W   = (const float*)d_in[1];   // (N_PROC,N_INPUT) fp32
    const float* PO  = (const float*)d_in[2];   // (N_PROC,D_MODEL) fp32
    const int*   idx = (const int*)d_in[3];     // (B,K_IN) int32
    float* out = (float*)d_out;                 // (B,S,D_MODEL) fp32

    // ws: sel 8388608 | scores 524288 | topk 8192 | WgHi 2097152 | WgLo 2097152
    char* w = (char*)d_ws;
    u16*   sel    = (u16*)w;
    float* scores = (float*)(w + (size_t)8388608);
    int*   topk   = (int*)(w + (size_t)8912896);
    u16*   WgHi   = (u16*)(w + (size_t)8921088);
    u16*   WgLo   = (u16*)(w + (size_t)11018240);

    k0_prep<<<dim3(NB, NPROC / 128), 256, 0, stream>>>(W, idx, WgHi, WgLo);
    k1_scores<<<dim3(NPROC / 128, NB, NSEG), 256, 0, stream>>>(A, WgHi, WgLo, scores);
    k2_topk<<<dim3(NB, 4), 256, 0, stream>>>(scores, topk);
    k3_selacts<<<dim3(NKP / 128, NB, NS / 128), 256, 0, stream>>>(A, WgHi, topk, sel);
    k4_mfma<<<dim3(NDM / 128, NS / 128, NB), 256, 0, stream>>>(sel, PO, topk, out);
}

// Round 8
// 162.288 us; speedup vs baseline: 56.8023x; 1.0296x over previous
//
#include <hip/hip_runtime.h>
#include <hip/hip_bf16.h>

// ProcessNeurons: B=8, S=2048, K_IN=128, D_MODEL=1024, N_INPUT=256,
// N_PROC=1024, K_PROC=256. Inputs fp32 (+int32 idx), output fp32.
// R5: k4->MFMA (9218->258us). R6: k2 parallel (->183us). R7: k1/k3 MFMA
// (->167us; k1 stall-bound, FETCH 35MB, occ 11%). R8: XCD-pin b=blockIdx&7
// (A/Wg L2-resident per XCD), k0a pre-split A, k1 BK=32 + 80B-pad LDS
// (42KB -> 3 blocks/CU). Score math bit-identical to R7.
#define NB    8
#define NS    2048
#define NKIN  128
#define NPROC 1024
#define NIN   256
#define NDM   1024
#define NKP   256
#define NSEG  16

typedef unsigned short u16;
typedef unsigned int   u32;
typedef __attribute__((ext_vector_type(4))) u16   u16x4;
typedef __attribute__((ext_vector_type(8))) u16   u16x8;
typedef __attribute__((ext_vector_type(4))) float f32x4;
typedef __attribute__((ext_vector_type(8))) short bf16x8;   // MFMA A/B frag
typedef __attribute__((ext_vector_type(4))) float f32x4v;   // MFMA C/D frag

__device__ __forceinline__ float bf2f(u16 u) {
    union { u32 i; float f; } v; v.i = ((u32)u) << 16; return v.f;
}
__device__ __forceinline__ u16 f2bf(float f) {
    u32 x = __float_as_uint(f);
    u32 r = (x + 0x7FFFu + ((x >> 16) & 1u)) >> 16;   // RNE
    return (u16)r;
}
__device__ __forceinline__ float gelu_exact(float x) {
    return 0.5f * x * (1.0f + erff(x * 0.70710678118654752f));
}
__device__ __forceinline__ int clampi(int v, int hi) {
    return v < 0 ? 0 : (v > hi ? hi : v);
}

// ---------------------------------------------------------------------------
// K0a: split A -> AHi/ALo bf16 (once; removes redundant f2bf from k1/k3).
// grid 1024, block 256, 8 floats/thread. Memory-bound ~3us.
// ---------------------------------------------------------------------------
__global__ __launch_bounds__(256) void k0a_splitA(
        const float* __restrict__ A, u16* __restrict__ AHi,
        u16* __restrict__ ALo) {
    size_t i = ((size_t)blockIdx.x * 256 + threadIdx.x) * 8;
    if (i >= (size_t)NB * NS * NKIN) return;
    f32x4 a = *(const f32x4*)&A[i];
    f32x4 c = *(const f32x4*)&A[i + 4];
    u16x8 h, l;
    #pragma unroll
    for (int j = 0; j < 4; ++j) {
        u16 hj = f2bf(a[j]); h[j] = hj;     l[j]     = f2bf(a[j] - bf2f(hj));
        u16 hk = f2bf(c[j]); h[j + 4] = hk; l[j + 4] = f2bf(c[j] - bf2f(hk));
    }
    *(u16x8*)&AHi[i] = h;
    *(u16x8*)&ALo[i] = l;
}

// ---------------------------------------------------------------------------
// K0: pre-gather + split W columns: Wg{Hi,Lo}[b][p][k] = split(W[p, idx[b,k]])
// grid (NB, NPROC/128), block 256.
// ---------------------------------------------------------------------------
__global__ __launch_bounds__(256) void k0_prep(
        const float* __restrict__ W, const int* __restrict__ idx,
        u16* __restrict__ WgHi, u16* __restrict__ WgLo) {
    const int b  = blockIdx.x;
    const int p0 = blockIdx.y * 128;
    const int tid = threadIdx.x;
    __shared__ int idxs[NKIN];
    if (tid < NKIN) idxs[tid] = clampi(idx[b * NKIN + tid], NIN - 1);
    __syncthreads();
    for (int e = tid; e < 128 * NKIN; e += 256) {
        int p = p0 + (e >> 7), k = e & 127;
        float x  = W[p * NIN + idxs[k]];
        u16 hi   = f2bf(x);
        u16 lo   = f2bf(x - bf2f(hi));
        size_t o = (size_t)(b * NPROC + p) * NKIN + k;
        WgHi[o] = hi;
        WgLo[o] = lo;
    }
}

// ---------------------------------------------------------------------------
// K1 (split MFMA): scores[seg,b,p] = sum_{s in seg} gelu(sum_k A*Wsel)
// acc = Ahi*Whi + Ahi*Wlo + Alo*Whi. 128x128 tile, 4 waves 2x2, BK=32 x4.
// LDS rows padded to 80B (bank-slot (5r+s)%8 -> worst 2-way, free).
// XCD-pinned: b = blockIdx.x & 7 -> per-XCD L2 holds A[b]+Wg[b] (1.5MB).
// grid 1024 (1D), block 256.
// ---------------------------------------------------------------------------
__global__ __launch_bounds__(256) void k1_scores(
        const u16* __restrict__ AHi, const u16* __restrict__ ALo,
        const u16* __restrict__ WgHi, const u16* __restrict__ WgLo,
        float* __restrict__ scores) {
    const int lin  = blockIdx.x;
    const int b    = lin & 7;        // XCD via round-robin dispatch
    const int q    = lin >> 3;       // 0..127
    const int pblk = q & 7;
    const int seg  = q >> 3;         // 0..15
    const int p0 = pblk * 128, s0 = seg * 128;
    const int tid  = threadIdx.x;
    const int lane = tid & 63;
    const int wid  = tid >> 6;
    const int wr   = wid >> 1;       // s half
    const int wc   = wid & 1;        // p half

    __shared__ u16  Ah[128 * 40], Al[128 * 40];   // [s][k] 80B rows, 10KB ea
    __shared__ u16  Wh[128 * 40], Wl[128 * 40];   // [p][k]
    __shared__ float red[2][128];

    f32x4v acc[4][4] = {};

    for (int kc = 0; kc < 4; ++kc) {   // BK=32
        __syncthreads();
        for (int e = tid; e < 512; e += 256) {   // A: 128 rows x 4 chunks
            int r = e >> 2, g = e & 3;
            size_t src = (size_t)(b * NS + s0 + r) * NKIN + kc * 32 + g * 8;
            u32 off = (u32)r * 80 + (u32)g * 16;
            *(u16x8*)((char*)Ah + off) = *(const u16x8*)&AHi[src];
            *(u16x8*)((char*)Al + off) = *(const u16x8*)&ALo[src];
        }
        for (int e = tid; e < 512; e += 256) {   // W: 128 rows x 4 chunks
            int pp = e >> 2, g = e & 3;
            size_t src = (size_t)(b * NPROC + p0 + pp) * NKIN + kc * 32 + g * 8;
            u32 off = (u32)pp * 80 + (u32)g * 16;
            *(u16x8*)((char*)Wh + off) = *(const u16x8*)&WgHi[src];
            *(u16x8*)((char*)Wl + off) = *(const u16x8*)&WgLo[src];
        }
        __syncthreads();

        const u32 kb = (u32)(lane >> 4) * 16;
        bf16x8 wh[4], wl[4];
        #pragma unroll
        for (int n = 0; n < 4; ++n) {
            u32 col = (u32)(wc * 64 + n * 16 + (lane & 15));
            wh[n] = *(const bf16x8*)((const char*)Wh + col * 80 + kb);
            wl[n] = *(const bf16x8*)((const char*)Wl + col * 80 + kb);
        }
        #pragma unroll
        for (int m = 0; m < 4; ++m) {
            u32 row = (u32)(wr * 64 + m * 16 + (lane & 15));
            bf16x8 ah = *(const bf16x8*)((const char*)Ah + row * 80 + kb);
            bf16x8 al = *(const bf16x8*)((const char*)Al + row * 80 + kb);
            #pragma unroll
            for (int n = 0; n < 4; ++n) {
                acc[m][n] = __builtin_amdgcn_mfma_f32_16x16x32_bf16(
                    ah, wh[n], acc[m][n], 0, 0, 0);
                acc[m][n] = __builtin_amdgcn_mfma_f32_16x16x32_bf16(
                    ah, wl[n], acc[m][n], 0, 0, 0);
                acc[m][n] = __builtin_amdgcn_mfma_f32_16x16x32_bf16(
                    al, wh[n], acc[m][n], 0, 0, 0);
            }
        }
    }

    // epilogue: gelu + column (over s) reduction (identical to R7)
    float colsum[4] = {0.f, 0.f, 0.f, 0.f};
    #pragma unroll
    for (int n = 0; n < 4; ++n)
        #pragma unroll
        for (int m = 0; m < 4; ++m)
            #pragma unroll
            for (int j = 0; j < 4; ++j)
                colsum[n] += gelu_exact(acc[m][n][j]);
    #pragma unroll
    for (int n = 0; n < 4; ++n) {
        colsum[n] += __shfl_xor(colsum[n], 16, 64);
        colsum[n] += __shfl_xor(colsum[n], 32, 64);
    }
    if (lane < 16) {
        #pragma unroll
        for (int n = 0; n < 4; ++n)
            red[wr][wc * 64 + n * 16 + lane] = colsum[n];
    }
    __syncthreads();
    if (tid < 128)
        scores[(size_t)(seg * NB + b) * NPROC + p0 + tid] =
            red[0][tid] + red[1][tid];
}

// ---------------------------------------------------------------------------
// K2: top-k by stable rank count (value desc, index asc == lax.top_k).
// grid (NB,4), 256 threads, fixed-order segment sum (deterministic).
// ---------------------------------------------------------------------------
__global__ __launch_bounds__(256) void k2_topk(
        const float* __restrict__ scores, int* __restrict__ topk) {
    const int b  = blockIdx.x;
    const int pc = blockIdx.y;
    __shared__ float sc[NPROC];
    #pragma unroll
    for (int q = 0; q < 4; ++q) {
        int p = q * 256 + threadIdx.x;
        float v = 0.f;
        #pragma unroll
        for (int seg = 0; seg < NSEG; ++seg)
            v += scores[(size_t)(seg * NB + b) * NPROC + p];
        sc[p] = v;
    }
    __syncthreads();
    const int p = pc * 256 + threadIdx.x;
    const float v = sc[p];
    int rank = 0;
    #pragma unroll 4
    for (int jj = 0; jj < NPROC / 4; ++jj) {
        f32x4 s4 = *(const f32x4*)&sc[jj * 4];
        #pragma unroll
        for (int c = 0; c < 4; ++c) {
            int j = jj * 4 + c;
            rank += (s4[c] > v) || (s4[c] == v && j < p);
        }
    }
    if (rank < NKP) topk[b * NKP + rank] = p;
}

// ---------------------------------------------------------------------------
// K3 (MFMA, hi-only): sel[b,s,c] = gelu(sum_k A*W[topk[b,c]]), bf16 store.
// A staged from AHi (pure u16x8). XCD-pinned b. grid 256 (1D), block 256.
// ---------------------------------------------------------------------------
__global__ __launch_bounds__(256) void k3_selacts(
        const u16* __restrict__ AHi, const u16* __restrict__ WgHi,
        const int* __restrict__ topk, u16* __restrict__ sel) {
    const int lin  = blockIdx.x;
    const int b    = lin & 7;
    const int q    = lin >> 3;       // 0..31
    const int cblk = q & 1;
    const int sblk = q >> 1;         // 0..15
    const int c0g = cblk * 128, s0 = sblk * 128;
    const int tid  = threadIdx.x;
    const int lane = tid & 63;
    const int wid  = tid >> 6;
    const int wr   = wid >> 1;
    const int wc   = wid & 1;

    __shared__ int tcol[128];
    __shared__ u16 Ah[128 * 128];   // [s][k] swizzled 256B rows, 32KB
    __shared__ u16 Ws[128 * 128];   // [c][k] swizzled, 32KB

    if (tid < 128) tcol[tid] = clampi(topk[b * NKP + c0g + tid], NPROC - 1);
    __syncthreads();

    for (int e = tid; e < 2048; e += 256) {   // A: 128 rows x 16 chunks
        int r = e >> 4, g = e & 15;
        u32 off = (u32)r * 256 + (((u32)g ^ ((u32)r & 15)) << 4);
        *(u16x8*)((char*)Ah + off) =
            *(const u16x8*)&AHi[(size_t)(b * NS + s0 + r) * NKIN + g * 8];
    }
    for (int e = tid; e < 2048; e += 256) {   // W: 128 c-rows x 16 chunks
        int cc = e >> 4, g = e & 15;
        u32 off = (u32)cc * 256 + (((u32)g ^ ((u32)cc & 15)) << 4);
        *(u16x8*)((char*)Ws + off) =
            *(const u16x8*)&WgHi[(size_t)(b * NPROC + tcol[cc]) * NKIN + g * 8];
    }
    __syncthreads();

    f32x4v acc[4][4] = {};
    #pragma unroll
    for (int ks = 0; ks < 4; ++ks) {
        const u32 kbyte = (u32)(ks * 64 + (lane >> 4) * 16);
        bf16x8 af[4], bf[4];
        #pragma unroll
        for (int m = 0; m < 4; ++m) {
            u32 row = (u32)(wr * 64 + m * 16 + (lane & 15));
            u32 off = row * 256 + (kbyte ^ ((row & 15) << 4));
            af[m] = *(const bf16x8*)((const char*)Ah + off);
        }
        #pragma unroll
        for (int n = 0; n < 4; ++n) {
            u32 col = (u32)(wc * 64 + n * 16 + (lane & 15));
            u32 off = col * 256 + (kbyte ^ ((col & 15) << 4));
            bf[n] = *(const bf16x8*)((const char*)Ws + off);
        }
        #pragma unroll
        for (int m = 0; m < 4; ++m)
            #pragma unroll
            for (int n = 0; n < 4; ++n)
                acc[m][n] = __builtin_amdgcn_mfma_f32_16x16x32_bf16(
                    af[m], bf[n], acc[m][n], 0, 0, 0);
    }

    #pragma unroll
    for (int m = 0; m < 4; ++m) {
        const int rbase = s0 + wr * 64 + m * 16 + (lane >> 4) * 4;
        #pragma unroll
        for (int n = 0; n < 4; ++n) {
            const int col = c0g + wc * 64 + n * 16 + (lane & 15);
            #pragma unroll
            for (int j = 0; j < 4; ++j)
                sel[(size_t)(b * NS + rbase + j) * NKP + col] =
                    f2bf(gelu_exact(acc[m][n][j]));
        }
    }
}

// ---------------------------------------------------------------------------
// K4 (MFMA): out[b,s,d] = sum_c sel[b,s,c] * PO[topk[b,c], d], fp32 out.
// XCD-pinned b. grid 1024 (1D), block 256.
// ---------------------------------------------------------------------------
__global__ __launch_bounds__(256) void k4_mfma(
        const u16* __restrict__ sel, const float* __restrict__ PO,
        const int* __restrict__ topk, float* __restrict__ out) {
    const int lin  = blockIdx.x;
    const int b    = lin & 7;
    const int q    = lin >> 3;       // 0..127
    const int dblk = q & 7;
    const int sblk = q >> 3;         // 0..15
    const int d0 = dblk * 128, s0 = sblk * 128;
    const int tid  = threadIdx.x;
    const int lane = tid & 63;
    const int wid  = tid >> 6;
    const int wr   = wid >> 1;
    const int wc   = wid & 1;

    __shared__ int tloc[NKP];
    __shared__ u16 Alds[128 * 64];
    __shared__ u16 Blds[128 * 64];

    tloc[tid] = clampi(topk[b * NKP + tid], NPROC - 1);

    f32x4v acc[4][4] = {};

    for (int k0 = 0; k0 < NKP; k0 += 64) {
        __syncthreads();
        for (int e = tid; e < 1024; e += 256) {
            int r = e >> 3, g = e & 7;
            u16x8 v = *(const u16x8*)&sel[(size_t)(b * NS + s0 + r) * NKP + k0 + g * 8];
            int slot = g ^ (r & 7);
            *(u16x8*)&Alds[r * 64 + slot * 8] = v;
        }
        for (int e = tid; e < 1024; e += 256) {
            int kp = e >> 5, cg = e & 31;
            f32x4 p0v = *(const f32x4*)&PO[(size_t)tloc[k0 + kp * 2]     * NDM + d0 + cg * 4];
            f32x4 p1v = *(const f32x4*)&PO[(size_t)tloc[k0 + kp * 2 + 1] * NDM + d0 + cg * 4];
            #pragma unroll
            for (int j = 0; j < 4; ++j) {
                int n = cg * 4 + j;
                u32 pack = (u32)f2bf(p0v[j]) | ((u32)f2bf(p1v[j]) << 16);
                u32 byteoff = (u32)n * 128 + (((u32)kp * 4) ^ (((u32)n & 7) << 4));
                *(u32*)((char*)Blds + byteoff) = pack;
            }
        }
        __syncthreads();

        #pragma unroll
        for (int kk = 0; kk < 2; ++kk) {
            const u32 kbase2 = (u32)(kk * 64 + (lane >> 4) * 16);
            bf16x8 afrag[4], bfrag[4];
            #pragma unroll
            for (int m = 0; m < 4; ++m) {
                u32 row = (u32)(wr * 64 + m * 16 + (lane & 15));
                u32 byteoff = row * 128 + (kbase2 ^ ((row & 7) << 4));
                afrag[m] = *(const bf16x8*)((const char*)Alds + byteoff);
            }
            #pragma unroll
            for (int n = 0; n < 4; ++n) {
                u32 col = (u32)(wc * 64 + n * 16 + (lane & 15));
                u32 byteoff = col * 128 + (kbase2 ^ ((col & 7) << 4));
                bfrag[n] = *(const bf16x8*)((const char*)Blds + byteoff);
            }
            #pragma unroll
            for (int m = 0; m < 4; ++m)
                #pragma unroll
                for (int n = 0; n < 4; ++n)
                    acc[m][n] = __builtin_amdgcn_mfma_f32_16x16x32_bf16(
                        afrag[m], bfrag[n], acc[m][n], 0, 0, 0);
        }
    }

    #pragma unroll
    for (int m = 0; m < 4; ++m) {
        const int rbase = s0 + wr * 64 + m * 16 + (lane >> 4) * 4;
        #pragma unroll
        for (int n = 0; n < 4; ++n) {
            const int col = d0 + wc * 64 + n * 16 + (lane & 15);
            #pragma unroll
            for (int j = 0; j < 4; ++j)
                out[(size_t)(b * NS + rbase + j) * NDM + col] = acc[m][n][j];
        }
    }
}

// ---------------------------------------------------------------------------
extern "C" void kernel_launch(void* const* d_in, const int* in_sizes, int n_in,
                              void* d_out, int out_size, void* d_ws, size_t ws_size,
                              hipStream_t stream) {
    (void)in_sizes; (void)n_in; (void)out_size; (void)ws_size;
    const float* A   = (const float*)d_in[0];   // (B,S,K_IN) fp32
    const float* W   = (const float*)d_in[1];   // (N_PROC,N_INPUT) fp32
    const float* PO  = (const float*)d_in[2];   // (N_PROC,D_MODEL) fp32
    const int*   idx = (const int*)d_in[3];     // (B,K_IN) int32
    float* out = (float*)d_out;                 // (B,S,D_MODEL) fp32

    // ws: sel 8388608 | scores 524288 | topk 8192 | WgHi 2097152 |
    //     WgLo 2097152 | AHi 4194304 | ALo 4194304   (total 20.5 MB)
    char* w = (char*)d_ws;
    u16*   sel    = (u16*)w;
    float* scores = (float*)(w + (size_t)8388608);
    int*   topk   = (int*)(w + (size_t)8912896);
    u16*   WgHi   = (u16*)(w + (size_t)8921088);
    u16*   WgLo   = (u16*)(w + (size_t)11018240);
    u16*   AHi    = (u16*)(w + (size_t)13115392);
    u16*   ALo    = (u16*)(w + (size_t)17309696);

    k0a_splitA<<<1024, 256, 0, stream>>>(A, AHi, ALo);
    k0_prep<<<dim3(NB, NPROC / 128), 256, 0, stream>>>(W, idx, WgHi, WgLo);
    k1_scores<<<1024, 256, 0, stream>>>(AHi, ALo, WgHi, WgLo, scores);
    k2_topk<<<dim3(NB, 4), 256, 0, stream>>>(scores, topk);
    k3_selacts<<<256, 256, 0, stream>>>(AHi, WgHi, topk, sel);
    k4_mfma<<<1024, 256, 0, stream>>>(sel, PO, topk, out);
}

// Round 9
// 161.184 us; speedup vs baseline: 57.1911x; 1.0068x over previous
//
#include <hip/hip_runtime.h>
#include <hip/hip_bf16.h>

// ProcessNeurons: B=8, S=2048, K_IN=128, D_MODEL=1024, N_INPUT=256,
// N_PROC=1024, K_PROC=256. Inputs fp32 (+int32 idx), output fp32.
// R5: k4->MFMA (9218->258us). R6: k2 parallel (->183us). R7: k1/k3 MFMA.
// R8: XCD-pin + pre-split A (FETCH 35->6.4MB, time flat -> latency-bound).
// R9: k1 single-shot K=128 (128KB LDS, one barrier, k3-structure clone) —
// kills the 4x barrier-drained staging phases. Score math bit-identical.
#define NB    8
#define NS    2048
#define NKIN  128
#define NPROC 1024
#define NIN   256
#define NDM   1024
#define NKP   256
#define NSEG  16

typedef unsigned short u16;
typedef unsigned int   u32;
typedef __attribute__((ext_vector_type(4))) u16   u16x4;
typedef __attribute__((ext_vector_type(8))) u16   u16x8;
typedef __attribute__((ext_vector_type(4))) float f32x4;
typedef __attribute__((ext_vector_type(8))) short bf16x8;   // MFMA A/B frag
typedef __attribute__((ext_vector_type(4))) float f32x4v;   // MFMA C/D frag

__device__ __forceinline__ float bf2f(u16 u) {
    union { u32 i; float f; } v; v.i = ((u32)u) << 16; return v.f;
}
__device__ __forceinline__ u16 f2bf(float f) {
    u32 x = __float_as_uint(f);
    u32 r = (x + 0x7FFFu + ((x >> 16) & 1u)) >> 16;   // RNE
    return (u16)r;
}
__device__ __forceinline__ float gelu_exact(float x) {
    return 0.5f * x * (1.0f + erff(x * 0.70710678118654752f));
}
__device__ __forceinline__ int clampi(int v, int hi) {
    return v < 0 ? 0 : (v > hi ? hi : v);
}

// ---------------------------------------------------------------------------
// K0a: split A -> AHi/ALo bf16 (once). grid 1024, block 256.
// ---------------------------------------------------------------------------
__global__ __launch_bounds__(256) void k0a_splitA(
        const float* __restrict__ A, u16* __restrict__ AHi,
        u16* __restrict__ ALo) {
    size_t i = ((size_t)blockIdx.x * 256 + threadIdx.x) * 8;
    if (i >= (size_t)NB * NS * NKIN) return;
    f32x4 a = *(const f32x4*)&A[i];
    f32x4 c = *(const f32x4*)&A[i + 4];
    u16x8 h, l;
    #pragma unroll
    for (int j = 0; j < 4; ++j) {
        u16 hj = f2bf(a[j]); h[j] = hj;     l[j]     = f2bf(a[j] - bf2f(hj));
        u16 hk = f2bf(c[j]); h[j + 4] = hk; l[j + 4] = f2bf(c[j] - bf2f(hk));
    }
    *(u16x8*)&AHi[i] = h;
    *(u16x8*)&ALo[i] = l;
}

// ---------------------------------------------------------------------------
// K0: pre-gather + split W columns: Wg{Hi,Lo}[b][p][k] = split(W[p, idx[b,k]])
// grid (NB, NPROC/128), block 256.
// ---------------------------------------------------------------------------
__global__ __launch_bounds__(256) void k0_prep(
        const float* __restrict__ W, const int* __restrict__ idx,
        u16* __restrict__ WgHi, u16* __restrict__ WgLo) {
    const int b  = blockIdx.x;
    const int p0 = blockIdx.y * 128;
    const int tid = threadIdx.x;
    __shared__ int idxs[NKIN];
    if (tid < NKIN) idxs[tid] = clampi(idx[b * NKIN + tid], NIN - 1);
    __syncthreads();
    for (int e = tid; e < 128 * NKIN; e += 256) {
        int p = p0 + (e >> 7), k = e & 127;
        float x  = W[p * NIN + idxs[k]];
        u16 hi   = f2bf(x);
        u16 lo   = f2bf(x - bf2f(hi));
        size_t o = (size_t)(b * NPROC + p) * NKIN + k;
        WgHi[o] = hi;
        WgLo[o] = lo;
    }
}

// ---------------------------------------------------------------------------
// K1 (split MFMA, single-shot K): scores[seg,b,p] = sum_s gelu(sum_k A*Wsel)
// acc = Ahi*Whi + Ahi*Wlo + Alo*Whi (same FP order as R8 -> bit-identical).
// 128s x 128p tile, K=128 staged ONCE (128KB LDS, 1 block/CU), one barrier,
// then 192 MFMA + 64 ds_read_b128 per wave, no intermediate barriers.
// 256B LDS rows, (row&15)<<4 XOR swizzle (k3-proven). XCD-pinned b.
// grid 1024 (1D), block 256.
// ---------------------------------------------------------------------------
__global__ __launch_bounds__(256) void k1_scores(
        const u16* __restrict__ AHi, const u16* __restrict__ ALo,
        const u16* __restrict__ WgHi, const u16* __restrict__ WgLo,
        float* __restrict__ scores) {
    const int lin  = blockIdx.x;
    const int b    = lin & 7;        // XCD via round-robin dispatch
    const int q    = lin >> 3;       // 0..127
    const int pblk = q & 7;
    const int seg  = q >> 3;         // 0..15
    const int p0 = pblk * 128, s0 = seg * 128;
    const int tid  = threadIdx.x;
    const int lane = tid & 63;
    const int wid  = tid >> 6;
    const int wr   = wid >> 1;       // s half
    const int wc   = wid & 1;        // p half

    __shared__ u16  Ah[128 * 128], Al[128 * 128];   // [s][k] swz, 32KB each
    __shared__ u16  Wh[128 * 128], Wl[128 * 128];   // [p][k] swz, 32KB each
    __shared__ float red[2][128];

    // stage everything: per thread 8+8 iters, 32 x 16B L2 loads (full MLP)
    for (int e = tid; e < 2048; e += 256) {   // A: 128 rows x 16 chunks
        int r = e >> 4, g = e & 15;
        size_t src = (size_t)(b * NS + s0 + r) * NKIN + g * 8;
        u32 off = (u32)r * 256 + (((u32)g ^ ((u32)r & 15)) << 4);
        *(u16x8*)((char*)Ah + off) = *(const u16x8*)&AHi[src];
        *(u16x8*)((char*)Al + off) = *(const u16x8*)&ALo[src];
    }
    for (int e = tid; e < 2048; e += 256) {   // W: 128 p-rows x 16 chunks
        int pp = e >> 4, g = e & 15;
        size_t src = (size_t)(b * NPROC + p0 + pp) * NKIN + g * 8;
        u32 off = (u32)pp * 256 + (((u32)g ^ ((u32)pp & 15)) << 4);
        *(u16x8*)((char*)Wh + off) = *(const u16x8*)&WgHi[src];
        *(u16x8*)((char*)Wl + off) = *(const u16x8*)&WgLo[src];
    }
    __syncthreads();

    f32x4v acc[4][4] = {};
    #pragma unroll
    for (int ks = 0; ks < 4; ++ks) {          // K = 4 x 32
        const u32 kbyte = (u32)(ks * 64 + (lane >> 4) * 16);
        bf16x8 wh[4], wl[4];
        #pragma unroll
        for (int n = 0; n < 4; ++n) {
            u32 col = (u32)(wc * 64 + n * 16 + (lane & 15));
            u32 off = col * 256 + (kbyte ^ ((col & 15) << 4));
            wh[n] = *(const bf16x8*)((const char*)Wh + off);
            wl[n] = *(const bf16x8*)((const char*)Wl + off);
        }
        #pragma unroll
        for (int m = 0; m < 4; ++m) {
            u32 row = (u32)(wr * 64 + m * 16 + (lane & 15));
            u32 off = row * 256 + (kbyte ^ ((row & 15) << 4));
            bf16x8 ah = *(const bf16x8*)((const char*)Ah + off);
            bf16x8 al = *(const bf16x8*)((const char*)Al + off);
            #pragma unroll
            for (int n = 0; n < 4; ++n) {
                acc[m][n] = __builtin_amdgcn_mfma_f32_16x16x32_bf16(
                    ah, wh[n], acc[m][n], 0, 0, 0);
                acc[m][n] = __builtin_amdgcn_mfma_f32_16x16x32_bf16(
                    ah, wl[n], acc[m][n], 0, 0, 0);
                acc[m][n] = __builtin_amdgcn_mfma_f32_16x16x32_bf16(
                    al, wh[n], acc[m][n], 0, 0, 0);
            }
        }
    }

    // epilogue: gelu + column (over s) reduction (identical order to R8)
    float colsum[4] = {0.f, 0.f, 0.f, 0.f};
    #pragma unroll
    for (int n = 0; n < 4; ++n)
        #pragma unroll
        for (int m = 0; m < 4; ++m)
            #pragma unroll
            for (int j = 0; j < 4; ++j)
                colsum[n] += gelu_exact(acc[m][n][j]);
    #pragma unroll
    for (int n = 0; n < 4; ++n) {
        colsum[n] += __shfl_xor(colsum[n], 16, 64);
        colsum[n] += __shfl_xor(colsum[n], 32, 64);
    }
    if (lane < 16) {
        #pragma unroll
        for (int n = 0; n < 4; ++n)
            red[wr][wc * 64 + n * 16 + lane] = colsum[n];
    }
    __syncthreads();
    if (tid < 128)
        scores[(size_t)(seg * NB + b) * NPROC + p0 + tid] =
            red[0][tid] + red[1][tid];
}

// ---------------------------------------------------------------------------
// K2: top-k by stable rank count (value desc, index asc == lax.top_k).
// grid (NB,4), 256 threads, fixed-order segment sum (deterministic).
// ---------------------------------------------------------------------------
__global__ __launch_bounds__(256) void k2_topk(
        const float* __restrict__ scores, int* __restrict__ topk) {
    const int b  = blockIdx.x;
    const int pc = blockIdx.y;
    __shared__ float sc[NPROC];
    #pragma unroll
    for (int q = 0; q < 4; ++q) {
        int p = q * 256 + threadIdx.x;
        float v = 0.f;
        #pragma unroll
        for (int seg = 0; seg < NSEG; ++seg)
            v += scores[(size_t)(seg * NB + b) * NPROC + p];
        sc[p] = v;
    }
    __syncthreads();
    const int p = pc * 256 + threadIdx.x;
    const float v = sc[p];
    int rank = 0;
    #pragma unroll 4
    for (int jj = 0; jj < NPROC / 4; ++jj) {
        f32x4 s4 = *(const f32x4*)&sc[jj * 4];
        #pragma unroll
        for (int c = 0; c < 4; ++c) {
            int j = jj * 4 + c;
            rank += (s4[c] > v) || (s4[c] == v && j < p);
        }
    }
    if (rank < NKP) topk[b * NKP + rank] = p;
}

// ---------------------------------------------------------------------------
// K3 (MFMA, hi-only): sel[b,s,c] = gelu(sum_k A*W[topk[b,c]]), bf16 store.
// XCD-pinned b. grid 256 (1D), block 256.  (unchanged from R8)
// ---------------------------------------------------------------------------
__global__ __launch_bounds__(256) void k3_selacts(
        const u16* __restrict__ AHi, const u16* __restrict__ WgHi,
        const int* __restrict__ topk, u16* __restrict__ sel) {
    const int lin  = blockIdx.x;
    const int b    = lin & 7;
    const int q    = lin >> 3;       // 0..31
    const int cblk = q & 1;
    const int sblk = q >> 1;         // 0..15
    const int c0g = cblk * 128, s0 = sblk * 128;
    const int tid  = threadIdx.x;
    const int lane = tid & 63;
    const int wid  = tid >> 6;
    const int wr   = wid >> 1;
    const int wc   = wid & 1;

    __shared__ int tcol[128];
    __shared__ u16 Ah[128 * 128];   // [s][k] swizzled 256B rows, 32KB
    __shared__ u16 Ws[128 * 128];   // [c][k] swizzled, 32KB

    if (tid < 128) tcol[tid] = clampi(topk[b * NKP + c0g + tid], NPROC - 1);
    __syncthreads();

    for (int e = tid; e < 2048; e += 256) {   // A: 128 rows x 16 chunks
        int r = e >> 4, g = e & 15;
        u32 off = (u32)r * 256 + (((u32)g ^ ((u32)r & 15)) << 4);
        *(u16x8*)((char*)Ah + off) =
            *(const u16x8*)&AHi[(size_t)(b * NS + s0 + r) * NKIN + g * 8];
    }
    for (int e = tid; e < 2048; e += 256) {   // W: 128 c-rows x 16 chunks
        int cc = e >> 4, g = e & 15;
        u32 off = (u32)cc * 256 + (((u32)g ^ ((u32)cc & 15)) << 4);
        *(u16x8*)((char*)Ws + off) =
            *(const u16x8*)&WgHi[(size_t)(b * NPROC + tcol[cc]) * NKIN + g * 8];
    }
    __syncthreads();

    f32x4v acc[4][4] = {};
    #pragma unroll
    for (int ks = 0; ks < 4; ++ks) {
        const u32 kbyte = (u32)(ks * 64 + (lane >> 4) * 16);
        bf16x8 af[4], bf[4];
        #pragma unroll
        for (int m = 0; m < 4; ++m) {
            u32 row = (u32)(wr * 64 + m * 16 + (lane & 15));
            u32 off = row * 256 + (kbyte ^ ((row & 15) << 4));
            af[m] = *(const bf16x8*)((const char*)Ah + off);
        }
        #pragma unroll
        for (int n = 0; n < 4; ++n) {
            u32 col = (u32)(wc * 64 + n * 16 + (lane & 15));
            u32 off = col * 256 + (kbyte ^ ((col & 15) << 4));
            bf[n] = *(const bf16x8*)((const char*)Ws + off);
        }
        #pragma unroll
        for (int m = 0; m < 4; ++m)
            #pragma unroll
            for (int n = 0; n < 4; ++n)
                acc[m][n] = __builtin_amdgcn_mfma_f32_16x16x32_bf16(
                    af[m], bf[n], acc[m][n], 0, 0, 0);
    }

    #pragma unroll
    for (int m = 0; m < 4; ++m) {
        const int rbase = s0 + wr * 64 + m * 16 + (lane >> 4) * 4;
        #pragma unroll
        for (int n = 0; n < 4; ++n) {
            const int col = c0g + wc * 64 + n * 16 + (lane & 15);
            #pragma unroll
            for (int j = 0; j < 4; ++j)
                sel[(size_t)(b * NS + rbase + j) * NKP + col] =
                    f2bf(gelu_exact(acc[m][n][j]));
        }
    }
}

// ---------------------------------------------------------------------------
// K4 (MFMA): out[b,s,d] = sum_c sel[b,s,c] * PO[topk[b,c], d], fp32 out.
// XCD-pinned b. grid 1024 (1D), block 256.  (unchanged from R8)
// ---------------------------------------------------------------------------
__global__ __launch_bounds__(256) void k4_mfma(
        const u16* __restrict__ sel, const float* __restrict__ PO,
        const int* __restrict__ topk, float* __restrict__ out) {
    const int lin  = blockIdx.x;
    const int b    = lin & 7;
    const int q    = lin >> 3;       // 0..127
    const int dblk = q & 7;
    const int sblk = q >> 3;         // 0..15
    const int d0 = dblk * 128, s0 = sblk * 128;
    const int tid  = threadIdx.x;
    const int lane = tid & 63;
    const int wid  = tid >> 6;
    const int wr   = wid >> 1;
    const int wc   = wid & 1;

    __shared__ int tloc[NKP];
    __shared__ u16 Alds[128 * 64];
    __shared__ u16 Blds[128 * 64];

    tloc[tid] = clampi(topk[b * NKP + tid], NPROC - 1);

    f32x4v acc[4][4] = {};

    for (int k0 = 0; k0 < NKP; k0 += 64) {
        __syncthreads();
        for (int e = tid; e < 1024; e += 256) {
            int r = e >> 3, g = e & 7;
            u16x8 v = *(const u16x8*)&sel[(size_t)(b * NS + s0 + r) * NKP + k0 + g * 8];
            int slot = g ^ (r & 7);
            *(u16x8*)&Alds[r * 64 + slot * 8] = v;
        }
        for (int e = tid; e < 1024; e += 256) {
            int kp = e >> 5, cg = e & 31;
            f32x4 p0v = *(const f32x4*)&PO[(size_t)tloc[k0 + kp * 2]     * NDM + d0 + cg * 4];
            f32x4 p1v = *(const f32x4*)&PO[(size_t)tloc[k0 + kp * 2 + 1] * NDM + d0 + cg * 4];
            #pragma unroll
            for (int j = 0; j < 4; ++j) {
                int n = cg * 4 + j;
                u32 pack = (u32)f2bf(p0v[j]) | ((u32)f2bf(p1v[j]) << 16);
                u32 byteoff = (u32)n * 128 + (((u32)kp * 4) ^ (((u32)n & 7) << 4));
                *(u32*)((char*)Blds + byteoff) = pack;
            }
        }
        __syncthreads();

        #pragma unroll
        for (int kk = 0; kk < 2; ++kk) {
            const u32 kbase2 = (u32)(kk * 64 + (lane >> 4) * 16);
            bf16x8 afrag[4], bfrag[4];
            #pragma unroll
            for (int m = 0; m < 4; ++m) {
                u32 row = (u32)(wr * 64 + m * 16 + (lane & 15));
                u32 byteoff = row * 128 + (kbase2 ^ ((row & 7) << 4));
                afrag[m] = *(const bf16x8*)((const char*)Alds + byteoff);
            }
            #pragma unroll
            for (int n = 0; n < 4; ++n) {
                u32 col = (u32)(wc * 64 + n * 16 + (lane & 15));
                u32 byteoff = col * 128 + (kbase2 ^ ((col & 7) << 4));
                bfrag[n] = *(const bf16x8*)((const char*)Blds + byteoff);
            }
            #pragma unroll
            for (int m = 0; m < 4; ++m)
                #pragma unroll
                for (int n = 0; n < 4; ++n)
                    acc[m][n] = __builtin_amdgcn_mfma_f32_16x16x32_bf16(
                        afrag[m], bfrag[n], acc[m][n], 0, 0, 0);
        }
    }

    #pragma unroll
    for (int m = 0; m < 4; ++m) {
        const int rbase = s0 + wr * 64 + m * 16 + (lane >> 4) * 4;
        #pragma unroll
        for (int n = 0; n < 4; ++n) {
            const int col = d0 + wc * 64 + n * 16 + (lane & 15);
            #pragma unroll
            for (int j = 0; j < 4; ++j)
                out[(size_t)(b * NS + rbase + j) * NDM + col] = acc[m][n][j];
        }
    }
}

// ---------------------------------------------------------------------------
extern "C" void kernel_launch(void* const* d_in, const int* in_sizes, int n_in,
                              void* d_out, int out_size, void* d_ws, size_t ws_size,
                              hipStream_t stream) {
    (void)in_sizes; (void)n_in; (void)out_size; (void)ws_size;
    const float* A   = (const float*)d_in[0];   // (B,S,K_IN) fp32
    const float* W   = (const float*)d_in[1];   // (N_PROC,N_INPUT) fp32
    const float* PO  = (const float*)d_in[2];   // (N_PROC,D_MODEL) fp32
    const int*   idx = (const int*)d_in[3];     // (B,K_IN) int32
    float* out = (float*)d_out;                 // (B,S,D_MODEL) fp32

    // ws: sel 8388608 | scores 524288 | topk 8192 | WgHi 2097152 |
    //     WgLo 2097152 | AHi 4194304 | ALo 4194304   (total 20.5 MB)
    char* w = (char*)d_ws;
    u16*   sel    = (u16*)w;
    float* scores = (float*)(w + (size_t)8388608);
    int*   topk   = (int*)(w + (size_t)8912896);
    u16*   WgHi   = (u16*)(w + (size_t)8921088);
    u16*   WgLo   = (u16*)(w + (size_t)11018240);
    u16*   AHi    = (u16*)(w + (size_t)13115392);
    u16*   ALo    = (u16*)(w + (size_t)17309696);

    k0a_splitA<<<1024, 256, 0, stream>>>(A, AHi, ALo);
    k0_prep<<<dim3(NB, NPROC / 128), 256, 0, stream>>>(W, idx, WgHi, WgLo);
    k1_scores<<<1024, 256, 0, stream>>>(AHi, ALo, WgHi, WgLo, scores);
    k2_topk<<<dim3(NB, 4), 256, 0, stream>>>(scores, topk);
    k3_selacts<<<256, 256, 0, stream>>>(AHi, WgHi, topk, sel);
    k4_mfma<<<1024, 256, 0, stream>>>(sel, PO, topk, out);
}

// Round 10
// 141.093 us; speedup vs baseline: 65.3350x; 1.1424x over previous
//
#include <hip/hip_runtime.h>
#include <hip/hip_bf16.h>

// ProcessNeurons: B=8, S=2048, K_IN=128, D_MODEL=1024, N_INPUT=256,
// N_PROC=1024, K_PROC=256. Inputs fp32 (+int32 idx), output fp32.
// R5: k4 MFMA (9218->258). R6: k2 parallel (->183). R7: k1/k3 MFMA (->167).
// R8: XCD-pin+presplit (FETCH 35->6.4MB, flat). R9: single-shot k1 (flat;
// all pipes idle -> latency + too few resident waves). R10: k1 64x64 tiles,
// 66KB LDS, 2 blocks/CU, 4096 blocks — block-level overlap hides staging.
#define NB    8
#define NS    2048
#define NKIN  128
#define NPROC 1024
#define NIN   256
#define NDM   1024
#define NKP   256
#define NSEG  32     // k1 S-segments (NS/64)

typedef unsigned short u16;
typedef unsigned int   u32;
typedef __attribute__((ext_vector_type(4))) u16   u16x4;
typedef __attribute__((ext_vector_type(8))) u16   u16x8;
typedef __attribute__((ext_vector_type(4))) float f32x4;
typedef __attribute__((ext_vector_type(8))) short bf16x8;   // MFMA A/B frag
typedef __attribute__((ext_vector_type(4))) float f32x4v;   // MFMA C/D frag

__device__ __forceinline__ float bf2f(u16 u) {
    union { u32 i; float f; } v; v.i = ((u32)u) << 16; return v.f;
}
__device__ __forceinline__ u16 f2bf(float f) {
    u32 x = __float_as_uint(f);
    u32 r = (x + 0x7FFFu + ((x >> 16) & 1u)) >> 16;   // RNE
    return (u16)r;
}
__device__ __forceinline__ float gelu_exact(float x) {
    return 0.5f * x * (1.0f + erff(x * 0.70710678118654752f));
}
__device__ __forceinline__ int clampi(int v, int hi) {
    return v < 0 ? 0 : (v > hi ? hi : v);
}

// ---------------------------------------------------------------------------
// K0a: split A -> AHi/ALo bf16 (once). grid 1024, block 256.
// ---------------------------------------------------------------------------
__global__ __launch_bounds__(256) void k0a_splitA(
        const float* __restrict__ A, u16* __restrict__ AHi,
        u16* __restrict__ ALo) {
    size_t i = ((size_t)blockIdx.x * 256 + threadIdx.x) * 8;
    if (i >= (size_t)NB * NS * NKIN) return;
    f32x4 a = *(const f32x4*)&A[i];
    f32x4 c = *(const f32x4*)&A[i + 4];
    u16x8 h, l;
    #pragma unroll
    for (int j = 0; j < 4; ++j) {
        u16 hj = f2bf(a[j]); h[j] = hj;     l[j]     = f2bf(a[j] - bf2f(hj));
        u16 hk = f2bf(c[j]); h[j + 4] = hk; l[j + 4] = f2bf(c[j] - bf2f(hk));
    }
    *(u16x8*)&AHi[i] = h;
    *(u16x8*)&ALo[i] = l;
}

// ---------------------------------------------------------------------------
// K0: pre-gather + split W columns: Wg{Hi,Lo}[b][p][k] = split(W[p, idx[b,k]])
// grid (NB, NPROC/128), block 256.
// ---------------------------------------------------------------------------
__global__ __launch_bounds__(256) void k0_prep(
        const float* __restrict__ W, const int* __restrict__ idx,
        u16* __restrict__ WgHi, u16* __restrict__ WgLo) {
    const int b  = blockIdx.x;
    const int p0 = blockIdx.y * 128;
    const int tid = threadIdx.x;
    __shared__ int idxs[NKIN];
    if (tid < NKIN) idxs[tid] = clampi(idx[b * NKIN + tid], NIN - 1);
    __syncthreads();
    for (int e = tid; e < 128 * NKIN; e += 256) {
        int p = p0 + (e >> 7), k = e & 127;
        float x  = W[p * NIN + idxs[k]];
        u16 hi   = f2bf(x);
        u16 lo   = f2bf(x - bf2f(hi));
        size_t o = (size_t)(b * NPROC + p) * NKIN + k;
        WgHi[o] = hi;
        WgLo[o] = lo;
    }
}

// ---------------------------------------------------------------------------
// K1 (split MFMA, 64x64 tiles): scores[seg,b,p] = sum_s gelu(sum_k A*Wsel)
// acc = Ahi*Whi + Ahi*Wlo + Alo*Whi (per-frag order identical to R9).
// 64s x 64p tile, 4 waves (2x2 of 32x32 quadrants, 2x2 16x16 frags each),
// K=128 one-shot. LDS 66KB -> 2 blocks/CU; 4096 blocks -> 8 rounds with
// 2-deep block overlap for latency hiding. XCD-pinned b. grid 4096 (1D).
// ---------------------------------------------------------------------------
__global__ __launch_bounds__(256) void k1_scores(
        const u16* __restrict__ AHi, const u16* __restrict__ ALo,
        const u16* __restrict__ WgHi, const u16* __restrict__ WgLo,
        float* __restrict__ scores) {
    const int lin  = blockIdx.x;
    const int b    = lin & 7;        // XCD via round-robin dispatch
    const int q    = lin >> 3;       // 0..511
    const int pblk = q & 15;         // 0..15
    const int sblk = q >> 4;         // 0..31
    const int p0 = pblk * 64, s0 = sblk * 64;
    const int tid  = threadIdx.x;
    const int lane = tid & 63;
    const int wid  = tid >> 6;
    const int wr   = wid >> 1;       // s quadrant (0/1)
    const int wc   = wid & 1;        // p quadrant (0/1)

    __shared__ u16  Ah[64 * 128], Al[64 * 128];   // [s][k] swz, 16KB each
    __shared__ u16  Wh[64 * 128], Wl[64 * 128];   // [p][k] swz, 16KB each
    __shared__ float red[2][64];

    // stage: 64 rows x 16 chunks = 1024 tasks (4 iters/thread each for A, W)
    for (int e = tid; e < 1024; e += 256) {
        int r = e >> 4, g = e & 15;
        size_t src = (size_t)(b * NS + s0 + r) * NKIN + g * 8;
        u32 off = (u32)r * 256 + (((u32)g ^ ((u32)r & 15)) << 4);
        *(u16x8*)((char*)Ah + off) = *(const u16x8*)&AHi[src];
        *(u16x8*)((char*)Al + off) = *(const u16x8*)&ALo[src];
    }
    for (int e = tid; e < 1024; e += 256) {
        int pp = e >> 4, g = e & 15;
        size_t src = (size_t)(b * NPROC + p0 + pp) * NKIN + g * 8;
        u32 off = (u32)pp * 256 + (((u32)g ^ ((u32)pp & 15)) << 4);
        *(u16x8*)((char*)Wh + off) = *(const u16x8*)&WgHi[src];
        *(u16x8*)((char*)Wl + off) = *(const u16x8*)&WgLo[src];
    }
    __syncthreads();

    f32x4v acc[2][2] = {};
    #pragma unroll
    for (int ks = 0; ks < 4; ++ks) {          // K = 4 x 32
        const u32 kbyte = (u32)(ks * 64 + (lane >> 4) * 16);
        bf16x8 ah[2], al[2], wh[2], wl[2];
        #pragma unroll
        for (int m = 0; m < 2; ++m) {
            u32 row = (u32)(wr * 32 + m * 16 + (lane & 15));
            u32 off = row * 256 + (kbyte ^ ((row & 15) << 4));
            ah[m] = *(const bf16x8*)((const char*)Ah + off);
            al[m] = *(const bf16x8*)((const char*)Al + off);
        }
        #pragma unroll
        for (int n = 0; n < 2; ++n) {
            u32 col = (u32)(wc * 32 + n * 16 + (lane & 15));
            u32 off = col * 256 + (kbyte ^ ((col & 15) << 4));
            wh[n] = *(const bf16x8*)((const char*)Wh + off);
            wl[n] = *(const bf16x8*)((const char*)Wl + off);
        }
        #pragma unroll
        for (int m = 0; m < 2; ++m)
            #pragma unroll
            for (int n = 0; n < 2; ++n) {
                acc[m][n] = __builtin_amdgcn_mfma_f32_16x16x32_bf16(
                    ah[m], wh[n], acc[m][n], 0, 0, 0);
                acc[m][n] = __builtin_amdgcn_mfma_f32_16x16x32_bf16(
                    ah[m], wl[n], acc[m][n], 0, 0, 0);
                acc[m][n] = __builtin_amdgcn_mfma_f32_16x16x32_bf16(
                    al[m], wh[n], acc[m][n], 0, 0, 0);
            }
    }

    // epilogue: gelu + column (over s) reduction
    float colsum[2] = {0.f, 0.f};
    #pragma unroll
    for (int n = 0; n < 2; ++n)
        #pragma unroll
        for (int m = 0; m < 2; ++m)
            #pragma unroll
            for (int j = 0; j < 4; ++j)
                colsum[n] += gelu_exact(acc[m][n][j]);
    #pragma unroll
    for (int n = 0; n < 2; ++n) {
        colsum[n] += __shfl_xor(colsum[n], 16, 64);
        colsum[n] += __shfl_xor(colsum[n], 32, 64);
    }
    if (lane < 16) {
        #pragma unroll
        for (int n = 0; n < 2; ++n)
            red[wr][wc * 32 + n * 16 + lane] = colsum[n];
    }
    __syncthreads();
    if (tid < 64)
        scores[(size_t)(sblk * NB + b) * NPROC + p0 + tid] =
            red[0][tid] + red[1][tid];
}

// ---------------------------------------------------------------------------
// K2: top-k by stable rank count (value desc, index asc == lax.top_k).
// grid (NB,4), 256 threads, fixed-order segment sum (deterministic).
// ---------------------------------------------------------------------------
__global__ __launch_bounds__(256) void k2_topk(
        const float* __restrict__ scores, int* __restrict__ topk) {
    const int b  = blockIdx.x;
    const int pc = blockIdx.y;
    __shared__ float sc[NPROC];
    #pragma unroll
    for (int q = 0; q < 4; ++q) {
        int p = q * 256 + threadIdx.x;
        float v = 0.f;
        #pragma unroll
        for (int seg = 0; seg < NSEG; ++seg)
            v += scores[(size_t)(seg * NB + b) * NPROC + p];
        sc[p] = v;
    }
    __syncthreads();
    const int p = pc * 256 + threadIdx.x;
    const float v = sc[p];
    int rank = 0;
    #pragma unroll 4
    for (int jj = 0; jj < NPROC / 4; ++jj) {
        f32x4 s4 = *(const f32x4*)&sc[jj * 4];
        #pragma unroll
        for (int c = 0; c < 4; ++c) {
            int j = jj * 4 + c;
            rank += (s4[c] > v) || (s4[c] == v && j < p);
        }
    }
    if (rank < NKP) topk[b * NKP + rank] = p;
}

// ---------------------------------------------------------------------------
// K3 (MFMA, hi-only): sel[b,s,c] = gelu(sum_k A*W[topk[b,c]]), bf16 store.
// XCD-pinned b. grid 256 (1D), block 256.  (unchanged from R9)
// ---------------------------------------------------------------------------
__global__ __launch_bounds__(256) void k3_selacts(
        const u16* __restrict__ AHi, const u16* __restrict__ WgHi,
        const int* __restrict__ topk, u16* __restrict__ sel) {
    const int lin  = blockIdx.x;
    const int b    = lin & 7;
    const int q    = lin >> 3;       // 0..31
    const int cblk = q & 1;
    const int sblk = q >> 1;         // 0..15
    const int c0g = cblk * 128, s0 = sblk * 128;
    const int tid  = threadIdx.x;
    const int lane = tid & 63;
    const int wid  = tid >> 6;
    const int wr   = wid >> 1;
    const int wc   = wid & 1;

    __shared__ int tcol[128];
    __shared__ u16 Ah[128 * 128];   // [s][k] swizzled 256B rows, 32KB
    __shared__ u16 Ws[128 * 128];   // [c][k] swizzled, 32KB

    if (tid < 128) tcol[tid] = clampi(topk[b * NKP + c0g + tid], NPROC - 1);
    __syncthreads();

    for (int e = tid; e < 2048; e += 256) {   // A: 128 rows x 16 chunks
        int r = e >> 4, g = e & 15;
        u32 off = (u32)r * 256 + (((u32)g ^ ((u32)r & 15)) << 4);
        *(u16x8*)((char*)Ah + off) =
            *(const u16x8*)&AHi[(size_t)(b * NS + s0 + r) * NKIN + g * 8];
    }
    for (int e = tid; e < 2048; e += 256) {   // W: 128 c-rows x 16 chunks
        int cc = e >> 4, g = e & 15;
        u32 off = (u32)cc * 256 + (((u32)g ^ ((u32)cc & 15)) << 4);
        *(u16x8*)((char*)Ws + off) =
            *(const u16x8*)&WgHi[(size_t)(b * NPROC + tcol[cc]) * NKIN + g * 8];
    }
    __syncthreads();

    f32x4v acc[4][4] = {};
    #pragma unroll
    for (int ks = 0; ks < 4; ++ks) {
        const u32 kbyte = (u32)(ks * 64 + (lane >> 4) * 16);
        bf16x8 af[4], bf[4];
        #pragma unroll
        for (int m = 0; m < 4; ++m) {
            u32 row = (u32)(wr * 64 + m * 16 + (lane & 15));
            u32 off = row * 256 + (kbyte ^ ((row & 15) << 4));
            af[m] = *(const bf16x8*)((const char*)Ah + off);
        }
        #pragma unroll
        for (int n = 0; n < 4; ++n) {
            u32 col = (u32)(wc * 64 + n * 16 + (lane & 15));
            u32 off = col * 256 + (kbyte ^ ((col & 15) << 4));
            bf[n] = *(const bf16x8*)((const char*)Ws + off);
        }
        #pragma unroll
        for (int m = 0; m < 4; ++m)
            #pragma unroll
            for (int n = 0; n < 4; ++n)
                acc[m][n] = __builtin_amdgcn_mfma_f32_16x16x32_bf16(
                    af[m], bf[n], acc[m][n], 0, 0, 0);
    }

    #pragma unroll
    for (int m = 0; m < 4; ++m) {
        const int rbase = s0 + wr * 64 + m * 16 + (lane >> 4) * 4;
        #pragma unroll
        for (int n = 0; n < 4; ++n) {
            const int col = c0g + wc * 64 + n * 16 + (lane & 15);
            #pragma unroll
            for (int j = 0; j < 4; ++j)
                sel[(size_t)(b * NS + rbase + j) * NKP + col] =
                    f2bf(gelu_exact(acc[m][n][j]));
        }
    }
}

// ---------------------------------------------------------------------------
// K4 (MFMA): out[b,s,d] = sum_c sel[b,s,c] * PO[topk[b,c], d], fp32 out.
// XCD-pinned b. grid 1024 (1D), block 256.  (unchanged from R9)
// ---------------------------------------------------------------------------
__global__ __launch_bounds__(256) void k4_mfma(
        const u16* __restrict__ sel, const float* __restrict__ PO,
        const int* __restrict__ topk, float* __restrict__ out) {
    const int lin  = blockIdx.x;
    const int b    = lin & 7;
    const int q    = lin >> 3;       // 0..127
    const int dblk = q & 7;
    const int sblk = q >> 3;         // 0..15
    const int d0 = dblk * 128, s0 = sblk * 128;
    const int tid  = threadIdx.x;
    const int lane = tid & 63;
    const int wid  = tid >> 6;
    const int wr   = wid >> 1;
    const int wc   = wid & 1;

    __shared__ int tloc[NKP];
    __shared__ u16 Alds[128 * 64];
    __shared__ u16 Blds[128 * 64];

    tloc[tid] = clampi(topk[b * NKP + tid], NPROC - 1);

    f32x4v acc[4][4] = {};

    for (int k0 = 0; k0 < NKP; k0 += 64) {
        __syncthreads();
        for (int e = tid; e < 1024; e += 256) {
            int r = e >> 3, g = e & 7;
            u16x8 v = *(const u16x8*)&sel[(size_t)(b * NS + s0 + r) * NKP + k0 + g * 8];
            int slot = g ^ (r & 7);
            *(u16x8*)&Alds[r * 64 + slot * 8] = v;
        }
        for (int e = tid; e < 1024; e += 256) {
            int kp = e >> 5, cg = e & 31;
            f32x4 p0v = *(const f32x4*)&PO[(size_t)tloc[k0 + kp * 2]     * NDM + d0 + cg * 4];
            f32x4 p1v = *(const f32x4*)&PO[(size_t)tloc[k0 + kp * 2 + 1] * NDM + d0 + cg * 4];
            #pragma unroll
            for (int j = 0; j < 4; ++j) {
                int n = cg * 4 + j;
                u32 pack = (u32)f2bf(p0v[j]) | ((u32)f2bf(p1v[j]) << 16);
                u32 byteoff = (u32)n * 128 + (((u32)kp * 4) ^ (((u32)n & 7) << 4));
                *(u32*)((char*)Blds + byteoff) = pack;
            }
        }
        __syncthreads();

        #pragma unroll
        for (int kk = 0; kk < 2; ++kk) {
            const u32 kbase2 = (u32)(kk * 64 + (lane >> 4) * 16);
            bf16x8 afrag[4], bfrag[4];
            #pragma unroll
            for (int m = 0; m < 4; ++m) {
                u32 row = (u32)(wr * 64 + m * 16 + (lane & 15));
                u32 byteoff = row * 128 + (kbase2 ^ ((row & 7) << 4));
                afrag[m] = *(const bf16x8*)((const char*)Alds + byteoff);
            }
            #pragma unroll
            for (int n = 0; n < 4; ++n) {
                u32 col = (u32)(wc * 64 + n * 16 + (lane & 15));
                u32 byteoff = col * 128 + (kbase2 ^ ((col & 7) << 4));
                bfrag[n] = *(const bf16x8*)((const char*)Blds + byteoff);
            }
            #pragma unroll
            for (int m = 0; m < 4; ++m)
                #pragma unroll
                for (int n = 0; n < 4; ++n)
                    acc[m][n] = __builtin_amdgcn_mfma_f32_16x16x32_bf16(
                        afrag[m], bfrag[n], acc[m][n], 0, 0, 0);
        }
    }

    #pragma unroll
    for (int m = 0; m < 4; ++m) {
        const int rbase = s0 + wr * 64 + m * 16 + (lane >> 4) * 4;
        #pragma unroll
        for (int n = 0; n < 4; ++n) {
            const int col = d0 + wc * 64 + n * 16 + (lane & 15);
            #pragma unroll
            for (int j = 0; j < 4; ++j)
                out[(size_t)(b * NS + rbase + j) * NDM + col] = acc[m][n][j];
        }
    }
}

// ---------------------------------------------------------------------------
extern "C" void kernel_launch(void* const* d_in, const int* in_sizes, int n_in,
                              void* d_out, int out_size, void* d_ws, size_t ws_size,
                              hipStream_t stream) {
    (void)in_sizes; (void)n_in; (void)out_size; (void)ws_size;
    const float* A   = (const float*)d_in[0];   // (B,S,K_IN) fp32
    const float* W   = (const float*)d_in[1];   // (N_PROC,N_INPUT) fp32
    const float* PO  = (const float*)d_in[2];   // (N_PROC,D_MODEL) fp32
    const int*   idx = (const int*)d_in[3];     // (B,K_IN) int32
    float* out = (float*)d_out;                 // (B,S,D_MODEL) fp32

    // ws: sel 8388608 | scores 1048576 | topk 8192 | WgHi 2097152 |
    //     WgLo 2097152 | AHi 4194304 | ALo 4194304   (total 21.0 MB)
    char* w = (char*)d_ws;
    u16*   sel    = (u16*)w;
    float* scores = (float*)(w + (size_t)8388608);
    int*   topk   = (int*)(w + (size_t)9437184);
    u16*   WgHi   = (u16*)(w + (size_t)9445376);
    u16*   WgLo   = (u16*)(w + (size_t)11542528);
    u16*   AHi    = (u16*)(w + (size_t)13639680);
    u16*   ALo    = (u16*)(w + (size_t)17833984);

    k0a_splitA<<<1024, 256, 0, stream>>>(A, AHi, ALo);
    k0_prep<<<dim3(NB, NPROC / 128), 256, 0, stream>>>(W, idx, WgHi, WgLo);
    k1_scores<<<4096, 256, 0, stream>>>(AHi, ALo, WgHi, WgLo, scores);
    k2_topk<<<dim3(NB, 4), 256, 0, stream>>>(scores, topk);
    k3_selacts<<<256, 256, 0, stream>>>(AHi, WgHi, topk, sel);
    k4_mfma<<<1024, 256, 0, stream>>>(sel, PO, topk, out);
}